// Round 4
// baseline (609.422 us; speedup 1.0000x reference)
//
#include <hip/hip_runtime.h>
#include <hip/hip_bf16.h>

#define NROWS 16384      // 16*32*32
#define EDIM  256
#define NE    8192
#define OUT_N 4194304    // 16*256*32*32

typedef _Float16 v8h __attribute__((ext_vector_type(8)));
typedef _Float16 v4h __attribute__((ext_vector_type(4)));
typedef _Float16 h2  __attribute__((ext_vector_type(2)));
typedef float    v4f __attribute__((ext_vector_type(4)));

// ---- main-path ws layout (float units) ---- (16.2 MB < 17.1 MB proven)
#define OFF_S     0                        // 16384
#define OFF_E     16384                    // 8192
#define OFF_MARG  24576                    // 16384
#define OFF_IDX   40960                    // 16384 i32
#define OFF_CH    57600                    // 16384*128 fp16 = 1048576 float slots
#define OFF_ZFH   1106176                  // 16384*256 fp16 = 2097152 float slots
#define OFF_EFH   3203328                  // 8192*256 fp16 = 1048576 float slots
#define OFF_LOSSP 4251904                  // 512 block partials
#define WS_NEED_FLOATS 4252416

#define ESCALE   1048576.0f                // 2^20 (exact); descale 2^-19 on d
#define DESCALE  0x1p-19f

static __device__ __forceinline__ unsigned short to_fp16_bits(float v) {
    _Float16 h = (_Float16)v;
    return __builtin_bit_cast(unsigned short, h);
}

static __device__ __forceinline__ h2 h2bc(unsigned int u) {
    return __builtin_bit_cast(h2, u);
}

// fp16x2 dot with fp32 accumulate. v_dot2_f32_f16: products of exact fp16
// inputs, fp32 accumulate — same error class as the validated R7/R8
// fp16xfp16 refine bound (fallback: exact cvt + fp32 fma, even tighter).
static __device__ __forceinline__ float dot2f(h2 a, h2 b, float c) {
#if defined(__has_builtin)
#if __has_builtin(__builtin_amdgcn_fdot2)
    return __builtin_amdgcn_fdot2(a, b, c, false);
#else
    return fmaf((float)a.y, (float)b.y, fmaf((float)a.x, (float)b.x, c));
#endif
#else
    return fmaf((float)a.y, (float)b.y, fmaf((float)a.x, (float)b.x, c));
#endif
}

// =======================================================================
// k_pre (validated R6-R9, byte-identical to last passing version):
// z rows (S, MARG, z cvt fp16), emb (cvt*2^20 + E sums).
// =======================================================================
__global__ __launch_bounds__(256) void k_pre(const float* __restrict__ z,
                                             const float* __restrict__ emb,
                                             float* __restrict__ ws) {
    float* S = ws + OFF_S;
    float* E = ws + OFF_E;
    float* MARG = ws + OFF_MARG;
    unsigned short* zfh = (unsigned short*)(ws + OFF_ZFH);
    unsigned short* efh = (unsigned short*)(ws + OFF_EFH);

    const int blk = blockIdx.x, tid = threadIdx.x;

    __shared__ float T[64][260];
    __shared__ double SD[64][4];
    __shared__ double AD[64][4];

    if (blk < 256) {
        const int r0 = blk * 64;
        const int b = r0 >> 10, hw0 = r0 & 1023;   // 64-row tile never crosses b
        const int rr = tid & 63, kq = tid >> 6;
        const float* zp = z + (size_t)b * 262144 + hw0 + rr;
        double s = 0.0, a = 0.0;
#pragma unroll 8
        for (int kk = 0; kk < 64; ++kk) {
            int k = kq * 64 + kk;
            float v = zp[(size_t)k << 10];
            s += (double)v * (double)v;
            a += fabs((double)v);
            T[rr][k] = v;
        }
        SD[rr][kq] = s; AD[rr][kq] = a;
        __syncthreads();
        if (tid < 64) {
            double ss = SD[tid][0] + SD[tid][1] + SD[tid][2] + SD[tid][3];
            double aa = AD[tid][0] + AD[tid][1] + AD[tid][2] + AD[tid][3];
            S[r0 + tid] = (float)ss;
            MARG[r0 + tid] = 1.2e-4f + 6.5e-7f * (float)aa;
        }
        const int m = tid >> 2, koff = (tid & 3) * 64;
#pragma unroll
        for (int c = 0; c < 8; ++c) {
            unsigned short us[8];
#pragma unroll
            for (int j = 0; j < 8; ++j) us[j] = to_fp16_bits(T[m][koff + c * 8 + j]);
            *(uint4*)(zfh + (size_t)(r0 + m) * 256 + koff + c * 8) = *(uint4*)us;
        }
    } else {
        const int eb = blk - 256;
        const float* src = emb + (size_t)eb * 16384;
        unsigned short* dst = efh + (size_t)eb * 16384;
#pragma unroll
        for (int it = 0; it < 16; ++it) {
            int e4 = tid + it * 256;
            float4 v = ((const float4*)src)[e4];
            unsigned short us[4] = {to_fp16_bits(v.x * ESCALE), to_fp16_bits(v.y * ESCALE),
                                    to_fp16_bits(v.z * ESCALE), to_fp16_bits(v.w * ESCALE)};
            *(uint2*)(dst + (size_t)e4 * 4) = *(uint2*)us;
        }
        const int n0 = eb * 64;
        const int rr = tid & 63, kq = tid >> 6;
        const float* p = emb + (size_t)(n0 + rr) * 256 + kq * 64;
        double s = 0.0;
#pragma unroll 8
        for (int kk = 0; kk < 64; ++kk) { float v = p[kk]; s += (double)v * (double)v; }
        SD[rr][kq] = s;
        __syncthreads();
        if (tid < 64)
            E[n0 + tid] = (float)(SD[tid][0] + SD[tid][1] + SD[tid][2] + SD[tid][3]);
    }
}

// =======================================================================
// k_gemm (validated R6-R9, unchanged): fp16 MFMA 128x128, K=256; per-(row,
// 64-col chunk) min of d_approx stored fp16 rel to S[r]. Deterministic.
// =======================================================================
__global__ __launch_bounds__(256) void k_gemm(
    const unsigned short* __restrict__ zfh, const unsigned short* __restrict__ efh,
    const float* __restrict__ S, const float* __restrict__ E,
    _Float16* __restrict__ CH) {
    __shared__ __align__(16) unsigned short As[128 * 64];
    __shared__ __align__(16) unsigned short Bs[128 * 64];

    const int tid = threadIdx.x;
    const int lane = tid & 63, wave = tid >> 6;
    const int wm = (wave & 1) * 64, wn = (wave >> 1) * 64;
    const int row0 = blockIdx.x * 128, col0 = blockIdx.y * 128;
    const int lm = lane & 15, lq = lane >> 4;

    v4f acc[4][4];
#pragma unroll
    for (int i = 0; i < 4; ++i)
#pragma unroll
        for (int j = 0; j < 4; ++j) acc[i][j] = (v4f){0.f, 0.f, 0.f, 0.f};

    for (int kt = 0; kt < 4; ++kt) {
        const int kbase = kt * 64;
#pragma unroll
        for (int it = 0; it < 4; ++it) {
            int e = tid + it * 256;
            int m = e >> 3, c = e & 7;
            uint4 va = *(const uint4*)(zfh + (size_t)(row0 + m) * 256 + kbase + c * 8);
            *(uint4*)(As + m * 64 + ((c ^ (m & 7)) << 3)) = va;
            uint4 vb = *(const uint4*)(efh + (size_t)(col0 + m) * 256 + kbase + c * 8);
            *(uint4*)(Bs + m * 64 + ((c ^ (m & 7)) << 3)) = vb;
        }
        __syncthreads();
#pragma unroll
        for (int s = 0; s < 2; ++s) {
            v8h af[4], bfr[4];
#pragma unroll
            for (int fi = 0; fi < 4; ++fi) {
                int m = wm + fi * 16 + lm;
                int c = (s << 2) | lq;
                af[fi] = *(const v8h*)(As + m * 64 + ((c ^ (m & 7)) << 3));
            }
#pragma unroll
            for (int fj = 0; fj < 4; ++fj) {
                int n = wn + fj * 16 + lm;
                int c = (s << 2) | lq;
                bfr[fj] = *(const v8h*)(Bs + n * 64 + ((c ^ (n & 7)) << 3));
            }
#pragma unroll
            for (int fi = 0; fi < 4; ++fi)
#pragma unroll
                for (int fj = 0; fj < 4; ++fj)
                    acc[fi][fj] = __builtin_amdgcn_mfma_f32_16x16x32_f16(
                        af[fi], bfr[fj], acc[fi][fj], 0, 0, 0);
        }
        __syncthreads();
    }

    float Sl[16];
#pragma unroll
    for (int fi = 0; fi < 4; ++fi)
#pragma unroll
        for (int r = 0; r < 4; ++r)
            Sl[fi * 4 + r] = S[row0 + wm + fi * 16 + lq * 4 + r];
    float En[4];
#pragma unroll
    for (int fj = 0; fj < 4; ++fj) En[fj] = E[col0 + wn + fj * 16 + lm];

    float dmin[16];
#pragma unroll
    for (int fi = 0; fi < 4; ++fi)
#pragma unroll
        for (int r = 0; r < 4; ++r) {
            float dm = __builtin_inff();
#pragma unroll
            for (int fj = 0; fj < 4; ++fj) {
                float d = (Sl[fi * 4 + r] + En[fj]) - acc[fi][fj][r] * DESCALE;
                dm = fminf(dm, d);
            }
            dmin[fi * 4 + r] = dm;
        }
#pragma unroll
    for (int msk = 1; msk < 16; msk <<= 1)
#pragma unroll
        for (int i = 0; i < 16; ++i)
            dmin[i] = fminf(dmin[i], __shfl_xor(dmin[i], msk, 64));

    if (lm == 0) {
        const int cb = blockIdx.y * 2 + (wn >> 6);
#pragma unroll
        for (int i = 0; i < 16; ++i) {
            int fi = i >> 2, r = i & 3;
            int gm = row0 + wm + fi * 16 + lq * 4 + r;
            float rel = dmin[i] - Sl[i];             // Sterbenz: exact
            CH[(size_t)gm * 128 + cb] = (_Float16)rel;
        }
    }
}

// =======================================================================
// k_rescore v8 (R13): intra-row parallelism. R12 post-mortem: duration is
// floored by ONE row's serial chunk loop (worst row ~50-100 candidate
// chunks x ~4K cyc on a single wave); block-level balancing can't touch it.
//   - 1 row per block, 8 waves; candidate chunk #i -> wave (i&7):
//     worst-row serial chain / 8. No atomics, no persistence.
//   - refine: zfh x efh via v_dot2_f32_f16 (fp16 z, fp16 emb, fp32 accum)
//     = the validated R7/R8 error class (fp32-z refine was noted strictly
//     tighter than that bound; MB = 0.75*MARG covers fp16 z+e rounding:
//     ~2.4e-7*sum|z| vs 4.9e-7*sum|z| budget). Kills the 64MB fp32 z tile
//     staging entirely (R12: z staging was most of 135MB fetch).
//   - wave-local grun >= global refine min -> survivor superset (safe
//     direction); every exact minimizer is refined exactly in its owning
//     wave; min over 8 wave keys == serial key (key = (d-bits, js) lex,
//     d>0 bit-monotone). Deterministic: fixed assignment, fixed orders.
//   - exact fp32 chain: byte-identical values & ascending-k fmaf order,
//     z read directly (uniform broadcast loads), emb row broadcast.
// =======================================================================
__global__ __launch_bounds__(512) void k_rescore(
    const float* __restrict__ z, const float* __restrict__ emb,
    const float* __restrict__ S, const float* __restrict__ E,
    const float* __restrict__ MARG,
    const unsigned short* __restrict__ zfh,
    const unsigned short* __restrict__ efh,
    const _Float16* __restrict__ CH,
    int* __restrict__ IDX, float* __restrict__ idx_f) {
    __shared__ uint4 zh4[32];                  // row r of zfh: 256 fp16 = 512B
    __shared__ unsigned long long wkey[8];
    const int tid = threadIdx.x;
    const int lane = tid & 63, w = tid >> 6;   // 8 waves
    const int r = blockIdx.x;
    const int b = r >> 10, hw = r & 1023;

    if (tid < 32) zh4[tid] = ((const uint4*)(zfh + (size_t)r * 256))[tid];
    __syncthreads();

    // per-wave redundant (identical) candidate-set computation: no barrier
    float m0 = (float)CH[(size_t)r * 128 + lane];
    float m1 = (float)CH[(size_t)r * 128 + 64 + lane];
    float g = fminf(m0, m1);
#pragma unroll
    for (int off = 32; off; off >>= 1) g = fminf(g, __shfl_xor(g, off, 64));
    const float thr = g + MARG[r];
    const float MB  = 0.75f * MARG[r];
    const float Sr = S[r];

    unsigned long long p0 = __ballot(m0 <= thr);
    unsigned long long p1 = __ballot(m1 <= thr);

    const float* zb = z + ((size_t)b << 18) + hw;
    unsigned long long key = ~0ull;
    float grun = __builtin_inff();
    int ci = 0;                                // candidate ordinal (both halves)
    for (int half = 0; half < 2; ++half) {
        unsigned long long pm = half ? p1 : p0;
        while (pm) {                           // wave-uniform, ascending chunks
            int c = __ffsll((long long)pm) - 1; pm &= pm - 1;
            if (((ci++) & 7) != w) continue;   // round-robin chunk -> wave
            const int cb = half * 64 + c;
            const int j = (cb << 6) | lane;
            // ---- refine: fp16 z (LDS broadcast) x fp16 emb (scaled 2^20),
            // fp32 accum via dot2; 4 independent accumulators
            const uint4* ep = (const uint4*)(efh + ((size_t)j << 8));
            float a0 = 0.0f, a1 = 0.0f, a2 = 0.0f, a3 = 0.0f;
#pragma unroll 8
            for (int q = 0; q < 32; ++q) {
                uint4 ev = ep[q];
                uint4 zv = zh4[q];
                a0 = dot2f(h2bc(zv.x), h2bc(ev.x), a0);
                a1 = dot2f(h2bc(zv.y), h2bc(ev.y), a1);
                a2 = dot2f(h2bc(zv.z), h2bc(ev.z), a2);
                a3 = dot2f(h2bc(zv.w), h2bc(ev.w), a3);
            }
            float macc = (a0 + a1) + (a2 + a3);
            float dref = (Sr + E[j]) - macc * DESCALE;
            float lmin = dref;
#pragma unroll
            for (int off = 32; off; off >>= 1)
                lmin = fminf(lmin, __shfl_xor(lmin, off, 64));
            grun = fminf(grun, lmin);
            // superset-safe: wave-local grun >= refine min only adds survivors
            unsigned long long sm = __ballot(dref <= grun + MB);
            while (sm) {                       // rare survivors, ascending
                int s = __ffsll((long long)sm) - 1; sm &= sm - 1;
                const int js = (cb << 6) | s;
                // ---- exact fp32 chain (bit-identical): original z values,
                // ascending k, single fmaf chain; uniform broadcast loads
                const float4* ep4 = (const float4*)(emb + ((size_t)js << 8));
                float m = 0.0f;
#pragma unroll 8
                for (int k4 = 0; k4 < 64; ++k4) {
                    float4 e4 = ep4[k4];
                    m = fmaf(zb[(size_t)(k4 * 4 + 0) << 10], e4.x, m);
                    m = fmaf(zb[(size_t)(k4 * 4 + 1) << 10], e4.y, m);
                    m = fmaf(zb[(size_t)(k4 * 4 + 2) << 10], e4.z, m);
                    m = fmaf(zb[(size_t)(k4 * 4 + 3) << 10], e4.w, m);
                }
                float d = (Sr + E[js]) - 2.0f * m;   // d>0 -> bits monotone
                unsigned long long kk =
                    ((unsigned long long)__float_as_uint(d) << 32) | (unsigned)js;
                key = kk < key ? kk : key;     // lane-uniform
            }
        }
    }
    if (lane == 0) wkey[w] = key;
    __syncthreads();
    if (tid == 0) {
        unsigned long long kk = wkey[0];
#pragma unroll
        for (int i = 1; i < 8; ++i) kk = wkey[i] < kk ? wkey[i] : kk;
        int jj = (int)(kk & 0xFFFFFFFFull);
        IDX[r] = jj;
        idx_f[r] = (float)jj;
    }
}

// =======================================================================
// k_out v2 (validated R8/R9, unchanged) + k_fin (deterministic loss)
// =======================================================================
__global__ __launch_bounds__(256) void k_out(const float* __restrict__ z,
                                             const float* __restrict__ emb,
                                             const int* __restrict__ idx,
                                             float* __restrict__ out,
                                             float* __restrict__ lossp) {
    __shared__ __align__(16) float EB[32 * 260];
    __shared__ float red[256];
    __shared__ int ids[32];
    const int tid = threadIdx.x;
    const int r0 = blockIdx.x * 32;            // 32 consecutive rows, same b
    const int b = r0 >> 10, hw0 = r0 & 1023;

    if (tid < 32) ids[tid] = idx[r0 + tid];
    __syncthreads();
#pragma unroll
    for (int it = 0; it < 8; ++it) {
        int i = tid + it * 256;                // 0..2047
        int rr = i >> 6, k4 = i & 63;
        float4 v = *(const float4*)(emb + (size_t)ids[rr] * 256 + k4 * 4);
        *(float4*)(EB + rr * 260 + k4 * 4) = v;
    }
    __syncthreads();

    const float* zb = z + ((size_t)b << 18) + hw0;
    float*       ob = out + ((size_t)b << 18) + hw0;
    const int hq = tid & 7;
    const int cg = tid >> 3;
    float lsum = 0.0f;
#pragma unroll
    for (int it = 0; it < 8; ++it) {
        int c = it * 32 + cg;
        float4 zv = *(const float4*)(zb + (size_t)c * 1024 + hq * 4);
        float e0 = EB[(hq * 4 + 0) * 260 + c];
        float e1 = EB[(hq * 4 + 1) * 260 + c];
        float e2 = EB[(hq * 4 + 2) * 260 + c];
        float e3 = EB[(hq * 4 + 3) * 260 + c];
        float d0 = e0 - zv.x, d1 = e1 - zv.y, d2 = e2 - zv.z, d3 = e3 - zv.w;
        float4 ov = {zv.x + d0, zv.y + d1, zv.z + d2, zv.w + d3};
        *(float4*)(ob + (size_t)c * 1024 + hq * 4) = ov;
        lsum += d0 * d0 + d1 * d1 + d2 * d2 + d3 * d3;
    }
    red[tid] = lsum;
    __syncthreads();
    for (int off = 128; off; off >>= 1) {
        if (tid < off) red[tid] += red[tid + off];
        __syncthreads();
    }
    if (tid == 0) lossp[blockIdx.x] = red[0];
}

__global__ __launch_bounds__(256) void k_fin(const float* __restrict__ lossp,
                                             float* __restrict__ out_loss) {
    __shared__ float red[256];
    const int tid = threadIdx.x;
    red[tid] = lossp[tid] + lossp[tid + 256];
    __syncthreads();
    for (int off = 128; off; off >>= 1) {
        if (tid < off) red[tid] += red[tid + off];
        __syncthreads();
    }
    if (tid == 0) {
        float m = red[0] / 4194304.0f;
        out_loss[0] = m + 0.25f * m;
    }
}

// =======================================================================
// Fallback path (round-2 core, proven): used only if ws is too small.
// =======================================================================
#define FWS_S     0
#define FWS_E     (FWS_S + NROWS)
#define FWS_KEY   (FWS_E + NE)
#define FWS_IDX   (FWS_KEY + NROWS * 2)
#define FWS_LOSSP (FWS_IDX + NROWS)

__global__ void f_rowsum_z(const float* __restrict__ z, float* __restrict__ S) {
    int r = blockIdx.x * 256 + threadIdx.x;
    int b = r >> 10, hw = r & 1023;
    const float* p = z + (size_t)b * 262144 + hw;
    double s = 0.0;
#pragma unroll 8
    for (int c = 0; c < 256; ++c) { float v = p[(size_t)c * 1024]; s += (double)v * (double)v; }
    S[r] = (float)s;
}
__global__ void f_rowsum_e(const float* __restrict__ emb, float* __restrict__ E) {
    int row = blockIdx.x * 4 + (threadIdx.x >> 6);
    int lane = threadIdx.x & 63;
    const float* p = emb + (size_t)row * 256;
    double s = 0.0;
#pragma unroll
    for (int i = 0; i < 4; ++i) { float v = p[lane + i * 64]; s += (double)v * (double)v; }
    for (int off = 32; off; off >>= 1) s += __shfl_down(s, off, 64);
    if (lane == 0) E[row] = (float)s;
}
__global__ __launch_bounds__(256, 4) void f_gemm_argmin(
    const float* __restrict__ z, const float* __restrict__ emb,
    const float* __restrict__ S, const float* __restrict__ E,
    unsigned long long* __restrict__ keys) {
    __shared__ __align__(16) float As[32][128];
    __shared__ __align__(16) float Bs[32][133];
    const int tid = threadIdx.x;
    const int tx = tid & 15, ty = tid >> 4;
    const int row0 = blockIdx.x * 128, col0 = blockIdx.y * 128;
    const int b = row0 >> 10, hw0 = row0 & 1023;
    const float* zb = z + (size_t)b * 262144 + hw0;
    float acc[8][8];
#pragma unroll
    for (int i = 0; i < 8; ++i)
#pragma unroll
        for (int j = 0; j < 8; ++j) acc[i][j] = 0.0f;
    for (int kt = 0; kt < 8; ++kt) {
        const int kbase = kt * 32;
#pragma unroll
        for (int it = 0; it < 4; ++it) {
            int e = tid + it * 256;
            int k = e >> 5, m4 = (e & 31) << 2;
            *(float4*)&As[k][m4] = *(const float4*)(zb + (size_t)(kbase + k) * 1024 + m4);
        }
#pragma unroll
        for (int it = 0; it < 4; ++it) {
            int e = tid + it * 256;
            int n = e >> 3, k4 = (e & 7) << 2;
            float4 v = *(const float4*)(emb + (size_t)(col0 + n) * 256 + kbase + k4);
            Bs[k4 + 0][n] = v.x; Bs[k4 + 1][n] = v.y;
            Bs[k4 + 2][n] = v.z; Bs[k4 + 3][n] = v.w;
        }
        __syncthreads();
#pragma unroll 8
        for (int k = 0; k < 32; ++k) {
            float4 a0 = *(const float4*)&As[k][tx * 4];
            float4 a1 = *(const float4*)&As[k][64 + tx * 4];
            float4 b0 = *(const float4*)&Bs[k][ty * 4];
            float4 b1 = *(const float4*)&Bs[k][64 + ty * 4];
            float a_[8] = {a0.x, a0.y, a0.z, a0.w, a1.x, a1.y, a1.z, a1.w};
            float b_[8] = {b0.x, b0.y, b0.z, b0.w, b1.x, b1.y, b1.z, b1.w};
#pragma unroll
            for (int i = 0; i < 8; ++i)
#pragma unroll
                for (int j = 0; j < 8; ++j) acc[i][j] += a_[i] * b_[j];
        }
        __syncthreads();
    }
    float4 S0 = *(const float4*)(S + row0 + tx * 4);
    float4 S1 = *(const float4*)(S + row0 + 64 + tx * 4);
    float4 E0 = *(const float4*)(E + col0 + ty * 4);
    float4 E1 = *(const float4*)(E + col0 + 64 + ty * 4);
    float Sr[8] = {S0.x, S0.y, S0.z, S0.w, S1.x, S1.y, S1.z, S1.w};
    float Ec[8] = {E0.x, E0.y, E0.z, E0.w, E1.x, E1.y, E1.z, E1.w};
    unsigned long long best[8];
#pragma unroll
    for (int i = 0; i < 8; ++i) best[i] = ~0ull;
#pragma unroll
    for (int j = 0; j < 8; ++j) {
        int col = col0 + ((j < 4) ? (ty * 4 + j) : (64 + ty * 4 + j - 4));
#pragma unroll
        for (int i = 0; i < 8; ++i) {
            float t = Sr[i] + Ec[j];
            float d = t - 2.0f * acc[i][j];
            unsigned ud = __float_as_uint(d);
            ud = (ud & 0x80000000u) ? ~ud : (ud | 0x80000000u);
            unsigned long long key = ((unsigned long long)ud << 32) | (unsigned)col;
            if (key < best[i]) best[i] = key;
        }
    }
    __syncthreads();
    unsigned long long* Sk = (unsigned long long*)&As[0][0];
#pragma unroll
    for (int i = 0; i < 4; ++i) {
        Sk[ty * 128 + tx * 4 + i] = best[i];
        Sk[ty * 128 + 64 + tx * 4 + i] = best[4 + i];
    }
    __syncthreads();
    if (tid < 128) {
        unsigned long long m = ~0ull;
#pragma unroll
        for (int t = 0; t < 16; ++t) {
            unsigned long long v = Sk[t * 128 + tid];
            m = v < m ? v : m;
        }
        atomicMin(&keys[row0 + tid], m);
    }
}
__global__ void f_merge(const unsigned long long* __restrict__ keys,
                        int* __restrict__ idx, float* __restrict__ idx_f) {
    int r = blockIdx.x * 256 + threadIdx.x;
    int bestj = (int)(keys[r] & 0xFFFFFFFFull);
    idx[r] = bestj;
    idx_f[r] = (float)bestj;
}

extern "C" void kernel_launch(void* const* d_in, const int* in_sizes, int n_in,
                              void* d_out, int out_size, void* d_ws, size_t ws_size,
                              hipStream_t stream) {
    const float* z   = (const float*)d_in[0];
    const float* emb = (const float*)d_in[1];
    float* out = (float*)d_out;
    float* ws  = (float*)d_ws;

    if (ws_size >= (size_t)WS_NEED_FLOATS * 4) {
        float* S = ws + OFF_S;
        float* E = ws + OFF_E;
        float* MARG = ws + OFF_MARG;
        int* IDX = (int*)(ws + OFF_IDX);
        _Float16* CH = (_Float16*)(ws + OFF_CH);
        unsigned short* ZFH = (unsigned short*)(ws + OFF_ZFH);
        unsigned short* EFH = (unsigned short*)(ws + OFF_EFH);
        float* LOSSP = ws + OFF_LOSSP;

        k_pre<<<384, 256, 0, stream>>>(z, emb, ws);
        dim3 g(NROWS / 128, NE / 128);
        k_gemm<<<g, 256, 0, stream>>>(ZFH, EFH, S, E, CH);
        k_rescore<<<NROWS, 512, 0, stream>>>(z, emb, S, E, MARG, ZFH, EFH, CH,
                                             IDX, out + OUT_N + 1);
        k_out<<<NROWS / 32, 256, 0, stream>>>(z, emb, IDX, out, LOSSP);
        k_fin<<<1, 256, 0, stream>>>(LOSSP, out + OUT_N);
    } else {
        float* S = ws + FWS_S;
        float* E = ws + FWS_E;
        unsigned long long* KEYS = (unsigned long long*)(ws + FWS_KEY);
        int* IDX = (int*)(ws + FWS_IDX);
        float* LOSSP = ws + FWS_LOSSP;

        f_rowsum_z<<<NROWS / 256, 256, 0, stream>>>(z, S);
        f_rowsum_e<<<NE / 4, 256, 0, stream>>>(emb, E);
        hipMemsetAsync(KEYS, 0xFF, NROWS * sizeof(unsigned long long), stream);
        dim3 g(NROWS / 128, NE / 128);
        f_gemm_argmin<<<g, 256, 0, stream>>>(z, emb, S, E, KEYS);
        f_merge<<<NROWS / 256, 256, 0, stream>>>(KEYS, IDX, out + OUT_N + 1);
        k_out<<<NROWS / 32, 256, 0, stream>>>(z, emb, IDX, out, LOSSP);
        k_fin<<<1, 256, 0, stream>>>(LOSSP, out + OUT_N);
    }
}

// Round 7
// 281.970 us; speedup vs baseline: 2.1613x; 2.1613x over previous
//
#include <hip/hip_runtime.h>
#include <hip/hip_bf16.h>

#define NROWS 16384      // 16*32*32
#define EDIM  256
#define NE    8192
#define OUT_N 4194304    // 16*256*32*32

typedef _Float16 v8h __attribute__((ext_vector_type(8)));
typedef _Float16 v4h __attribute__((ext_vector_type(4)));
typedef _Float16 h2  __attribute__((ext_vector_type(2)));
typedef float    v4f __attribute__((ext_vector_type(4)));

// ---- main-path ws layout (float units) ---- (16.2 MB < 17.1 MB proven)
#define OFF_S     0                        // 16384
#define OFF_E     16384                    // 8192
#define OFF_MARG  24576                    // 16384
#define OFF_IDX   40960                    // 16384 i32
#define OFF_CH    57600                    // 16384*128 fp16 = 1048576 float slots
#define OFF_ZFH   1106176                  // 16384*256 fp16 = 2097152 float slots
#define OFF_EFH   3203328                  // 8192*256 fp16 = 1048576 float slots
#define OFF_LOSSP 4251904                  // 512 block partials
#define WS_NEED_FLOATS 4252416

#define ESCALE   1048576.0f                // 2^20 (exact); descale 2^-19 on d
#define DESCALE  0x1p-19f

static __device__ __forceinline__ unsigned short to_fp16_bits(float v) {
    _Float16 h = (_Float16)v;
    return __builtin_bit_cast(unsigned short, h);
}

static __device__ __forceinline__ h2 h2bc(unsigned int u) {
    return __builtin_bit_cast(h2, u);
}

// fp16x2 dot with fp32 accumulate (validated in R13 passing run: exact fp16
// inputs, fp32 accumulate — same error class as the R7/R8 refine bound).
static __device__ __forceinline__ float dot2f(h2 a, h2 b, float c) {
#if defined(__has_builtin)
#if __has_builtin(__builtin_amdgcn_fdot2)
    return __builtin_amdgcn_fdot2(a, b, c, false);
#else
    return fmaf((float)a.y, (float)b.y, fmaf((float)a.x, (float)b.x, c));
#endif
#else
    return fmaf((float)a.y, (float)b.y, fmaf((float)a.x, (float)b.x, c));
#endif
}

// =======================================================================
// k_pre (validated R6-R9, byte-identical to R0-passing version):
// z rows (S, MARG, z cvt fp16), emb (cvt*2^20 + E sums).
// =======================================================================
__global__ __launch_bounds__(256) void k_pre(const float* __restrict__ z,
                                             const float* __restrict__ emb,
                                             float* __restrict__ ws) {
    float* S = ws + OFF_S;
    float* E = ws + OFF_E;
    float* MARG = ws + OFF_MARG;
    unsigned short* zfh = (unsigned short*)(ws + OFF_ZFH);
    unsigned short* efh = (unsigned short*)(ws + OFF_EFH);

    const int blk = blockIdx.x, tid = threadIdx.x;

    __shared__ float T[64][260];
    __shared__ double SD[64][4];
    __shared__ double AD[64][4];

    if (blk < 256) {
        const int r0 = blk * 64;
        const int b = r0 >> 10, hw0 = r0 & 1023;   // 64-row tile never crosses b
        const int rr = tid & 63, kq = tid >> 6;
        const float* zp = z + (size_t)b * 262144 + hw0 + rr;
        double s = 0.0, a = 0.0;
#pragma unroll 8
        for (int kk = 0; kk < 64; ++kk) {
            int k = kq * 64 + kk;
            float v = zp[(size_t)k << 10];
            s += (double)v * (double)v;
            a += fabs((double)v);
            T[rr][k] = v;
        }
        SD[rr][kq] = s; AD[rr][kq] = a;
        __syncthreads();
        if (tid < 64) {
            double ss = SD[tid][0] + SD[tid][1] + SD[tid][2] + SD[tid][3];
            double aa = AD[tid][0] + AD[tid][1] + AD[tid][2] + AD[tid][3];
            S[r0 + tid] = (float)ss;
            MARG[r0 + tid] = 1.2e-4f + 6.5e-7f * (float)aa;
        }
        const int m = tid >> 2, koff = (tid & 3) * 64;
#pragma unroll
        for (int c = 0; c < 8; ++c) {
            unsigned short us[8];
#pragma unroll
            for (int j = 0; j < 8; ++j) us[j] = to_fp16_bits(T[m][koff + c * 8 + j]);
            *(uint4*)(zfh + (size_t)(r0 + m) * 256 + koff + c * 8) = *(uint4*)us;
        }
    } else {
        const int eb = blk - 256;
        const float* src = emb + (size_t)eb * 16384;
        unsigned short* dst = efh + (size_t)eb * 16384;
#pragma unroll
        for (int it = 0; it < 16; ++it) {
            int e4 = tid + it * 256;
            float4 v = ((const float4*)src)[e4];
            unsigned short us[4] = {to_fp16_bits(v.x * ESCALE), to_fp16_bits(v.y * ESCALE),
                                    to_fp16_bits(v.z * ESCALE), to_fp16_bits(v.w * ESCALE)};
            *(uint2*)(dst + (size_t)e4 * 4) = *(uint2*)us;
        }
        const int n0 = eb * 64;
        const int rr = tid & 63, kq = tid >> 6;
        const float* p = emb + (size_t)(n0 + rr) * 256 + kq * 64;
        double s = 0.0;
#pragma unroll 8
        for (int kk = 0; kk < 64; ++kk) { float v = p[kk]; s += (double)v * (double)v; }
        SD[rr][kq] = s;
        __syncthreads();
        if (tid < 64)
            E[n0 + tid] = (float)(SD[tid][0] + SD[tid][1] + SD[tid][2] + SD[tid][3]);
    }
}

// =======================================================================
// k_gemm (validated R6-R9, byte-identical R0): fp16 MFMA 128x128, K=256;
// per-(row, 64-col chunk) min of d_approx stored fp16 rel to S[r].
// =======================================================================
__global__ __launch_bounds__(256) void k_gemm(
    const unsigned short* __restrict__ zfh, const unsigned short* __restrict__ efh,
    const float* __restrict__ S, const float* __restrict__ E,
    _Float16* __restrict__ CH) {
    __shared__ __align__(16) unsigned short As[128 * 64];
    __shared__ __align__(16) unsigned short Bs[128 * 64];

    const int tid = threadIdx.x;
    const int lane = tid & 63, wave = tid >> 6;
    const int wm = (wave & 1) * 64, wn = (wave >> 1) * 64;
    const int row0 = blockIdx.x * 128, col0 = blockIdx.y * 128;
    const int lm = lane & 15, lq = lane >> 4;

    v4f acc[4][4];
#pragma unroll
    for (int i = 0; i < 4; ++i)
#pragma unroll
        for (int j = 0; j < 4; ++j) acc[i][j] = (v4f){0.f, 0.f, 0.f, 0.f};

    for (int kt = 0; kt < 4; ++kt) {
        const int kbase = kt * 64;
#pragma unroll
        for (int it = 0; it < 4; ++it) {
            int e = tid + it * 256;
            int m = e >> 3, c = e & 7;
            uint4 va = *(const uint4*)(zfh + (size_t)(row0 + m) * 256 + kbase + c * 8);
            *(uint4*)(As + m * 64 + ((c ^ (m & 7)) << 3)) = va;
            uint4 vb = *(const uint4*)(efh + (size_t)(col0 + m) * 256 + kbase + c * 8);
            *(uint4*)(Bs + m * 64 + ((c ^ (m & 7)) << 3)) = vb;
        }
        __syncthreads();
#pragma unroll
        for (int s = 0; s < 2; ++s) {
            v8h af[4], bfr[4];
#pragma unroll
            for (int fi = 0; fi < 4; ++fi) {
                int m = wm + fi * 16 + lm;
                int c = (s << 2) | lq;
                af[fi] = *(const v8h*)(As + m * 64 + ((c ^ (m & 7)) << 3));
            }
#pragma unroll
            for (int fj = 0; fj < 4; ++fj) {
                int n = wn + fj * 16 + lm;
                int c = (s << 2) | lq;
                bfr[fj] = *(const v8h*)(Bs + n * 64 + ((c ^ (n & 7)) << 3));
            }
#pragma unroll
            for (int fi = 0; fi < 4; ++fi)
#pragma unroll
                for (int fj = 0; fj < 4; ++fj)
                    acc[fi][fj] = __builtin_amdgcn_mfma_f32_16x16x32_f16(
                        af[fi], bfr[fj], acc[fi][fj], 0, 0, 0);
        }
        __syncthreads();
    }

    float Sl[16];
#pragma unroll
    for (int fi = 0; fi < 4; ++fi)
#pragma unroll
        for (int r = 0; r < 4; ++r)
            Sl[fi * 4 + r] = S[row0 + wm + fi * 16 + lq * 4 + r];
    float En[4];
#pragma unroll
    for (int fj = 0; fj < 4; ++fj) En[fj] = E[col0 + wn + fj * 16 + lm];

    float dmin[16];
#pragma unroll
    for (int fi = 0; fi < 4; ++fi)
#pragma unroll
        for (int r = 0; r < 4; ++r) {
            float dm = __builtin_inff();
#pragma unroll
            for (int fj = 0; fj < 4; ++fj) {
                float d = (Sl[fi * 4 + r] + En[fj]) - acc[fi][fj][r] * DESCALE;
                dm = fminf(dm, d);
            }
            dmin[fi * 4 + r] = dm;
        }
#pragma unroll
    for (int msk = 1; msk < 16; msk <<= 1)
#pragma unroll
        for (int i = 0; i < 16; ++i)
            dmin[i] = fminf(dmin[i], __shfl_xor(dmin[i], msk, 64));

    if (lm == 0) {
        const int cb = blockIdx.y * 2 + (wn >> 6);
#pragma unroll
        for (int i = 0; i < 16; ++i) {
            int fi = i >> 2, r = i & 3;
            int gm = row0 + wm + fi * 16 + lq * 4 + r;
            float rel = dmin[i] - Sl[i];             // Sterbenz: exact
            CH[(size_t)gm * 128 + cb] = (_Float16)rel;
        }
    }
}

// =======================================================================
// k_rescore v11 (R16): R15's cooperative-coalesced refine with the
// redistribution FIXED. R15 bug: __shfl evaluates the source operand on
// the SOURCE lane — sel must be selected by the source's own (lane&7),
// and the source lane for dest d is ((d&7)<<3)|(d>>3). R15 had
// sel=dP[lane>>3], src=(lane&7)<<3 which is correct only on the diagonal
// (8/64 lanes) -> scrambled dref -> absmax 7974.
//   Mapping proof: group g = lanes 8g..8g+7 all hold (post-butterfly,
//   bitwise-identical) dP[p] = dref(col j0+8p+g) for p=0..7. Dest d wants
//   col j0+d = (p=d>>3, g=d&7). Source s=((d&7)<<3)|(d>>3): s>>3=d&7 (in
//   group d&7), sel_s=dP[s&7]=dP[d>>3]. Example d=10 -> s=17, group 2,
//   dP[1] = col j0+8+2 = j0+10. Correct for all 64 lanes.
// Everything else is the R0-passing algorithm verbatim: candidate chunks
// by thr=g+MARG; survivors dref<=grun+MB (stale-high grun superset-safe);
// byte-identical serial exact fp32 chain; key=(d-bits,js) min.
// Refine error class: fp16xfp16 products (exact in fp32), fp32 accum,
// tree order — tighter than the R13-passing 64-deep chain class; MB holds.
// =======================================================================
__global__ __launch_bounds__(1024) void k_rescore(
    const float* __restrict__ z, const float* __restrict__ emb,
    const float* __restrict__ S, const float* __restrict__ E,
    const float* __restrict__ MARG,
    const unsigned short* __restrict__ zfh,
    const unsigned short* __restrict__ efh,
    const _Float16* __restrict__ CH,
    int* __restrict__ IDX, float* __restrict__ idx_f) {
    __shared__ float zs[32][260];
    __shared__ uint4 zh4[32][32];              // 32 rows of zfh (fp16 pairs)
    const int tid = threadIdx.x;
    const int r0 = blockIdx.x * 32;            // 32 consecutive rows, same b
    const int b = r0 >> 10, hw0 = r0 & 1023;
    const float* zb = z + ((size_t)b << 18) + hw0;

    // stage 32x256 fp32 z: float4 over hw (full 128B lines, coalesced) — R0
#pragma unroll
    for (int it = 0; it < 2; ++it) {
        int slot = tid + it * 1024;            // 0..2047 float4 slots
        int c = slot >> 3, h4 = (slot & 7) << 2;
        float4 v = *(const float4*)(zb + (size_t)c * 1024 + h4);
        zs[h4 + 0][c] = v.x; zs[h4 + 1][c] = v.y;
        zs[h4 + 2][c] = v.z; zs[h4 + 3][c] = v.w;
    }
    // stage 32 zfh rows (16KB, coalesced)
    {
        int rr = tid >> 5, q = tid & 31;
        zh4[rr][q] = ((const uint4*)(zfh + (size_t)(r0 + rr) * 256))[q];
    }
    __syncthreads();

    const int lane = tid & 63, wave = tid >> 6;   // 16 waves
    const int gid = lane >> 3, lg = lane & 7;     // col-group / lane-in-group
#pragma unroll
    for (int rw = 0; rw < 2; ++rw) {
        const int rl = wave * 2 + rw;
        const int r = r0 + rl;

        float m0 = (float)CH[(size_t)r * 128 + lane];
        float m1 = (float)CH[(size_t)r * 128 + 64 + lane];
        float g = fminf(m0, m1);
#pragma unroll
        for (int off = 32; off; off >>= 1) g = fminf(g, __shfl_xor(g, off, 64));
        const float thr = g + MARG[r];
        const float MB  = 0.75f * MARG[r];
        const float Sr = S[r];

        unsigned long long p0 = __ballot(m0 <= thr);
        unsigned long long p1 = __ballot(m1 <= thr);

        unsigned long long key = ~0ull;
        float grun = __builtin_inff();
        for (int half = 0; half < 2; ++half) {
            unsigned long long pm = half ? p1 : p0;
            while (pm) {                       // wave-uniform, ascending chunks
                int c = __ffsll((long long)pm) - 1; pm &= pm - 1;
                const int cb = half * 64 + c;
                const int j0 = cb << 6;
                // ---- cooperative coalesced refine: 8 passes x 8 cols;
                // 8 lanes/col, each covering 4x(8 dims) at stride 64
                float dP[8];
#pragma unroll
                for (int p = 0; p < 8; ++p) {
                    const int j = j0 + p * 8 + gid;
                    const uint4* ep = (const uint4*)(efh + ((size_t)j << 8));
                    float a0 = 0.0f, a1 = 0.0f;
#pragma unroll
                    for (int q = 0; q < 4; ++q) {
                        uint4 ev = ep[q * 8 + lg];       // dims (q*8+lg)*8..+7
                        uint4 zv = zh4[rl][q * 8 + lg];  // same dims of z
                        a0 = dot2f(h2bc(zv.x), h2bc(ev.x), a0);
                        a1 = dot2f(h2bc(zv.y), h2bc(ev.y), a1);
                        a0 = dot2f(h2bc(zv.z), h2bc(ev.z), a0);
                        a1 = dot2f(h2bc(zv.w), h2bc(ev.w), a1);
                    }
                    float acc = a0 + a1;
                    // butterfly over the 8-lane group: commutative adds ->
                    // identical bits on all 8 lanes (deterministic)
                    acc += __shfl_xor(acc, 1, 64);
                    acc += __shfl_xor(acc, 2, 64);
                    acc += __shfl_xor(acc, 4, 64);
                    dP[p] = (Sr + E[j]) - acc * DESCALE;
                }
                // redistribute (FIXED): source lane selects by ITS OWN lg;
                // dest d reads source ((d&7)<<3)|(d>>3) which holds
                // dP[d>>3] of group d&7 = col j0+d.
                float sel = dP[0];
                sel = (lg == 1) ? dP[1] : sel;
                sel = (lg == 2) ? dP[2] : sel;
                sel = (lg == 3) ? dP[3] : sel;
                sel = (lg == 4) ? dP[4] : sel;
                sel = (lg == 5) ? dP[5] : sel;
                sel = (lg == 6) ? dP[6] : sel;
                sel = (lg == 7) ? dP[7] : sel;
                float dref = __shfl(sel, ((lane & 7) << 3) | (lane >> 3), 64);
                // ---- R0 survivor logic verbatim
                float lmin = dref;
#pragma unroll
                for (int off = 32; off; off >>= 1)
                    lmin = fminf(lmin, __shfl_xor(lmin, off, 64));
                grun = fminf(grun, lmin);
                // superset-safe: stale-high grun only adds survivors
                unsigned long long sm = __ballot(dref <= grun + MB);
                while (sm) {                   // ~1.2 survivors/row, ascending
                    int s = __ffsll((long long)sm) - 1; sm &= sm - 1;
                    const int js = (cb << 6) | s;
                    // ---- exact fp32 chain (bit-identical): LDS-broadcast z,
                    // broadcast emb row, ascending k
                    const float4* ep4 = (const float4*)(emb + ((size_t)js << 8));
                    float m = 0.0f;
#pragma unroll 8
                    for (int k4 = 0; k4 < 64; ++k4) {
                        float4 e4 = ep4[k4];
                        m = fmaf(zs[rl][k4 * 4 + 0], e4.x, m);
                        m = fmaf(zs[rl][k4 * 4 + 1], e4.y, m);
                        m = fmaf(zs[rl][k4 * 4 + 2], e4.z, m);
                        m = fmaf(zs[rl][k4 * 4 + 3], e4.w, m);
                    }
                    float d = (Sr + E[js]) - 2.0f * m;   // d>0 -> bits monotone
                    unsigned long long kk =
                        ((unsigned long long)__float_as_uint(d) << 32) | (unsigned)js;
                    key = kk < key ? kk : key; // lane-uniform
                }
            }
        }
        if (lane == 0) {
            int j = (int)(key & 0xFFFFFFFFull);
            IDX[r] = j;
            idx_f[r] = (float)j;
        }
    }
}

// =======================================================================
// k_out v2 (validated R8/R9, unchanged) + k_fin (deterministic loss)
// =======================================================================
__global__ __launch_bounds__(256) void k_out(const float* __restrict__ z,
                                             const float* __restrict__ emb,
                                             const int* __restrict__ idx,
                                             float* __restrict__ out,
                                             float* __restrict__ lossp) {
    __shared__ __align__(16) float EB[32 * 260];
    __shared__ float red[256];
    __shared__ int ids[32];
    const int tid = threadIdx.x;
    const int r0 = blockIdx.x * 32;            // 32 consecutive rows, same b
    const int b = r0 >> 10, hw0 = r0 & 1023;

    if (tid < 32) ids[tid] = idx[r0 + tid];
    __syncthreads();
#pragma unroll
    for (int it = 0; it < 8; ++it) {
        int i = tid + it * 256;                // 0..2047
        int rr = i >> 6, k4 = i & 63;
        float4 v = *(const float4*)(emb + (size_t)ids[rr] * 256 + k4 * 4);
        *(float4*)(EB + rr * 260 + k4 * 4) = v;
    }
    __syncthreads();

    const float* zb = z + ((size_t)b << 18) + hw0;
    float*       ob = out + ((size_t)b << 18) + hw0;
    const int hq = tid & 7;
    const int cg = tid >> 3;
    float lsum = 0.0f;
#pragma unroll
    for (int it = 0; it < 8; ++it) {
        int c = it * 32 + cg;
        float4 zv = *(const float4*)(zb + (size_t)c * 1024 + hq * 4);
        float e0 = EB[(hq * 4 + 0) * 260 + c];
        float e1 = EB[(hq * 4 + 1) * 260 + c];
        float e2 = EB[(hq * 4 + 2) * 260 + c];
        float e3 = EB[(hq * 4 + 3) * 260 + c];
        float d0 = e0 - zv.x, d1 = e1 - zv.y, d2 = e2 - zv.z, d3 = e3 - zv.w;
        float4 ov = {zv.x + d0, zv.y + d1, zv.z + d2, zv.w + d3};
        *(float4*)(ob + (size_t)c * 1024 + hq * 4) = ov;
        lsum += d0 * d0 + d1 * d1 + d2 * d2 + d3 * d3;
    }
    red[tid] = lsum;
    __syncthreads();
    for (int off = 128; off; off >>= 1) {
        if (tid < off) red[tid] += red[tid + off];
        __syncthreads();
    }
    if (tid == 0) lossp[blockIdx.x] = red[0];
}

__global__ __launch_bounds__(256) void k_fin(const float* __restrict__ lossp,
                                             float* __restrict__ out_loss) {
    __shared__ float red[256];
    const int tid = threadIdx.x;
    red[tid] = lossp[tid] + lossp[tid + 256];
    __syncthreads();
    for (int off = 128; off; off >>= 1) {
        if (tid < off) red[tid] += red[tid + off];
        __syncthreads();
    }
    if (tid == 0) {
        float m = red[0] / 4194304.0f;
        out_loss[0] = m + 0.25f * m;
    }
}

// =======================================================================
// Fallback path (round-2 core, proven): used only if ws is too small.
// =======================================================================
#define FWS_S     0
#define FWS_E     (FWS_S + NROWS)
#define FWS_KEY   (FWS_E + NE)
#define FWS_IDX   (FWS_KEY + NROWS * 2)
#define FWS_LOSSP (FWS_IDX + NROWS)

__global__ void f_rowsum_z(const float* __restrict__ z, float* __restrict__ S) {
    int r = blockIdx.x * 256 + threadIdx.x;
    int b = r >> 10, hw = r & 1023;
    const float* p = z + (size_t)b * 262144 + hw;
    double s = 0.0;
#pragma unroll 8
    for (int c = 0; c < 256; ++c) { float v = p[(size_t)c * 1024]; s += (double)v * (double)v; }
    S[r] = (float)s;
}
__global__ void f_rowsum_e(const float* __restrict__ emb, float* __restrict__ E) {
    int row = blockIdx.x * 4 + (threadIdx.x >> 6);
    int lane = threadIdx.x & 63;
    const float* p = emb + (size_t)row * 256;
    double s = 0.0;
#pragma unroll
    for (int i = 0; i < 4; ++i) { float v = p[lane + i * 64]; s += (double)v * (double)v; }
    for (int off = 32; off; off >>= 1) s += __shfl_down(s, off, 64);
    if (lane == 0) E[row] = (float)s;
}
__global__ __launch_bounds__(256, 4) void f_gemm_argmin(
    const float* __restrict__ z, const float* __restrict__ emb,
    const float* __restrict__ S, const float* __restrict__ E,
    unsigned long long* __restrict__ keys) {
    __shared__ __align__(16) float As[32][128];
    __shared__ __align__(16) float Bs[32][133];
    const int tid = threadIdx.x;
    const int tx = tid & 15, ty = tid >> 4;
    const int row0 = blockIdx.x * 128, col0 = blockIdx.y * 128;
    const int b = row0 >> 10, hw0 = row0 & 1023;
    const float* zb = z + (size_t)b * 262144 + hw0;
    float acc[8][8];
#pragma unroll
    for (int i = 0; i < 8; ++i)
#pragma unroll
        for (int j = 0; j < 8; ++j) acc[i][j] = 0.0f;
    for (int kt = 0; kt < 8; ++kt) {
        const int kbase = kt * 32;
#pragma unroll
        for (int it = 0; it < 4; ++it) {
            int e = tid + it * 256;
            int k = e >> 5, m4 = (e & 31) << 2;
            *(float4*)&As[k][m4] = *(const float4*)(zb + (size_t)(kbase + k) * 1024 + m4);
        }
#pragma unroll
        for (int it = 0; it < 4; ++it) {
            int e = tid + it * 256;
            int n = e >> 3, k4 = (e & 7) << 2;
            float4 v = *(const float4*)(emb + (size_t)(col0 + n) * 256 + kbase + k4);
            Bs[k4 + 0][n] = v.x; Bs[k4 + 1][n] = v.y;
            Bs[k4 + 2][n] = v.z; Bs[k4 + 3][n] = v.w;
        }
        __syncthreads();
#pragma unroll 8
        for (int k = 0; k < 32; ++k) {
            float4 a0 = *(const float4*)&As[k][tx * 4];
            float4 a1 = *(const float4*)&As[k][64 + tx * 4];
            float4 b0 = *(const float4*)&Bs[k][ty * 4];
            float4 b1 = *(const float4*)&Bs[k][64 + ty * 4];
            float a_[8] = {a0.x, a0.y, a0.z, a0.w, a1.x, a1.y, a1.z, a1.w};
            float b_[8] = {b0.x, b0.y, b0.z, b0.w, b1.x, b1.y, b1.z, b1.w};
#pragma unroll
            for (int i = 0; i < 8; ++i)
#pragma unroll
                for (int j = 0; j < 8; ++j) acc[i][j] += a_[i] * b_[j];
        }
        __syncthreads();
    }
    float4 S0 = *(const float4*)(S + row0 + tx * 4);
    float4 S1 = *(const float4*)(S + row0 + 64 + tx * 4);
    float4 E0 = *(const float4*)(E + col0 + ty * 4);
    float4 E1 = *(const float4*)(E + col0 + 64 + ty * 4);
    float Sr[8] = {S0.x, S0.y, S0.z, S0.w, S1.x, S1.y, S1.z, S1.w};
    float Ec[8] = {E0.x, E0.y, E0.z, E0.w, E1.x, E1.y, E1.z, E1.w};
    unsigned long long best[8];
#pragma unroll
    for (int i = 0; i < 8; ++i) best[i] = ~0ull;
#pragma unroll
    for (int j = 0; j < 8; ++j) {
        int col = col0 + ((j < 4) ? (ty * 4 + j) : (64 + ty * 4 + j - 4));
#pragma unroll
        for (int i = 0; i < 8; ++i) {
            float t = Sr[i] + Ec[j];
            float d = t - 2.0f * acc[i][j];
            unsigned ud = __float_as_uint(d);
            ud = (ud & 0x80000000u) ? ~ud : (ud | 0x80000000u);
            unsigned long long key = ((unsigned long long)ud << 32) | (unsigned)col;
            if (key < best[i]) best[i] = key;
        }
    }
    __syncthreads();
    unsigned long long* Sk = (unsigned long long*)&As[0][0];
#pragma unroll
    for (int i = 0; i < 4; ++i) {
        Sk[ty * 128 + tx * 4 + i] = best[i];
        Sk[ty * 128 + 64 + tx * 4 + i] = best[4 + i];
    }
    __syncthreads();
    if (tid < 128) {
        unsigned long long m = ~0ull;
#pragma unroll
        for (int t = 0; t < 16; ++t) {
            unsigned long long v = Sk[t * 128 + tid];
            m = v < m ? v : m;
        }
        atomicMin(&keys[row0 + tid], m);
    }
}
__global__ void f_merge(const unsigned long long* __restrict__ keys,
                        int* __restrict__ idx, float* __restrict__ idx_f) {
    int r = blockIdx.x * 256 + threadIdx.x;
    int bestj = (int)(keys[r] & 0xFFFFFFFFull);
    idx[r] = bestj;
    idx_f[r] = (float)bestj;
}

extern "C" void kernel_launch(void* const* d_in, const int* in_sizes, int n_in,
                              void* d_out, int out_size, void* d_ws, size_t ws_size,
                              hipStream_t stream) {
    const float* z   = (const float*)d_in[0];
    const float* emb = (const float*)d_in[1];
    float* out = (float*)d_out;
    float* ws  = (float*)d_ws;

    if (ws_size >= (size_t)WS_NEED_FLOATS * 4) {
        float* S = ws + OFF_S;
        float* E = ws + OFF_E;
        float* MARG = ws + OFF_MARG;
        int* IDX = (int*)(ws + OFF_IDX);
        _Float16* CH = (_Float16*)(ws + OFF_CH);
        unsigned short* ZFH = (unsigned short*)(ws + OFF_ZFH);
        unsigned short* EFH = (unsigned short*)(ws + OFF_EFH);
        float* LOSSP = ws + OFF_LOSSP;

        k_pre<<<384, 256, 0, stream>>>(z, emb, ws);
        dim3 g(NROWS / 128, NE / 128);
        k_gemm<<<g, 256, 0, stream>>>(ZFH, EFH, S, E, CH);
        k_rescore<<<NROWS / 32, 1024, 0, stream>>>(z, emb, S, E, MARG, ZFH, EFH,
                                                   CH, IDX, out + OUT_N + 1);
        k_out<<<NROWS / 32, 256, 0, stream>>>(z, emb, IDX, out, LOSSP);
        k_fin<<<1, 256, 0, stream>>>(LOSSP, out + OUT_N);
    } else {
        float* S = ws + FWS_S;
        float* E = ws + FWS_E;
        unsigned long long* KEYS = (unsigned long long*)(ws + FWS_KEY);
        int* IDX = (int*)(ws + FWS_IDX);
        float* LOSSP = ws + FWS_LOSSP;

        f_rowsum_z<<<NROWS / 256, 256, 0, stream>>>(z, S);
        f_rowsum_e<<<NE / 4, 256, 0, stream>>>(emb, E);
        hipMemsetAsync(KEYS, 0xFF, NROWS * sizeof(unsigned long long), stream);
        dim3 g(NROWS / 128, NE / 128);
        f_gemm_argmin<<<g, 256, 0, stream>>>(z, emb, S, E, KEYS);
        f_merge<<<NROWS / 256, 256, 0, stream>>>(KEYS, IDX, out + OUT_N + 1);
        k_out<<<NROWS / 32, 256, 0, stream>>>(z, emb, IDX, out, LOSSP);
        k_fin<<<1, 256, 0, stream>>>(LOSSP, out + OUT_N);
    }
}

// Round 8
// 279.972 us; speedup vs baseline: 2.1767x; 1.0071x over previous
//
#include <hip/hip_runtime.h>
#include <hip/hip_bf16.h>

#define NROWS 16384      // 16*32*32
#define EDIM  256
#define NE    8192
#define OUT_N 4194304    // 16*256*32*32

typedef _Float16 v8h __attribute__((ext_vector_type(8)));
typedef _Float16 v4h __attribute__((ext_vector_type(4)));
typedef _Float16 h2  __attribute__((ext_vector_type(2)));
typedef float    v4f __attribute__((ext_vector_type(4)));

// ---- main-path ws layout (float units) ---- (16.2 MB < 17.1 MB proven)
#define OFF_S     0                        // 16384
#define OFF_E     16384                    // 8192
#define OFF_MARG  24576                    // 16384
#define OFF_IDX   40960                    // 16384 i32
#define OFF_CH    57600                    // 16384*128 fp16 = 1048576 float slots
#define OFF_ZFH   1106176                  // 16384*256 fp16 = 2097152 float slots
#define OFF_EFH   3203328                  // 8192*256 fp16 = 1048576 float slots
#define OFF_LOSSP 4251904                  // 512 block partials
#define WS_NEED_FLOATS 4252416

#define ESCALE   1048576.0f                // 2^20 (exact); descale 2^-19 on d
#define DESCALE  0x1p-19f

static __device__ __forceinline__ unsigned short to_fp16_bits(float v) {
    _Float16 h = (_Float16)v;
    return __builtin_bit_cast(unsigned short, h);
}

static __device__ __forceinline__ h2 h2bc(unsigned int u) {
    return __builtin_bit_cast(h2, u);
}

// async global->LDS, 16B per lane (wave-uniform LDS base + lane*16; global
// source per-lane). Guide §5: width=16 is the m97 staging path.
static __device__ __forceinline__ void gl_lds16(const void* g, void* l) {
    __builtin_amdgcn_global_load_lds(
        (const __attribute__((address_space(1))) unsigned int*)g,
        (__attribute__((address_space(3))) unsigned int*)l, 16, 0, 0);
}

// fp16x2 dot with fp32 accumulate (validated in R16 passing run: exact fp16
// inputs, fp32 accumulate — same error class as the R7/R8 refine bound).
static __device__ __forceinline__ float dot2f(h2 a, h2 b, float c) {
#if defined(__has_builtin)
#if __has_builtin(__builtin_amdgcn_fdot2)
    return __builtin_amdgcn_fdot2(a, b, c, false);
#else
    return fmaf((float)a.y, (float)b.y, fmaf((float)a.x, (float)b.x, c));
#endif
#else
    return fmaf((float)a.y, (float)b.y, fmaf((float)a.x, (float)b.x, c));
#endif
}

// =======================================================================
// k_pre (validated R6-R9, byte-identical to R0-passing version):
// z rows (S, MARG, z cvt fp16), emb (cvt*2^20 + E sums).
// =======================================================================
__global__ __launch_bounds__(256) void k_pre(const float* __restrict__ z,
                                             const float* __restrict__ emb,
                                             float* __restrict__ ws) {
    float* S = ws + OFF_S;
    float* E = ws + OFF_E;
    float* MARG = ws + OFF_MARG;
    unsigned short* zfh = (unsigned short*)(ws + OFF_ZFH);
    unsigned short* efh = (unsigned short*)(ws + OFF_EFH);

    const int blk = blockIdx.x, tid = threadIdx.x;

    __shared__ float T[64][260];
    __shared__ double SD[64][4];
    __shared__ double AD[64][4];

    if (blk < 256) {
        const int r0 = blk * 64;
        const int b = r0 >> 10, hw0 = r0 & 1023;   // 64-row tile never crosses b
        const int rr = tid & 63, kq = tid >> 6;
        const float* zp = z + (size_t)b * 262144 + hw0 + rr;
        double s = 0.0, a = 0.0;
#pragma unroll 8
        for (int kk = 0; kk < 64; ++kk) {
            int k = kq * 64 + kk;
            float v = zp[(size_t)k << 10];
            s += (double)v * (double)v;
            a += fabs((double)v);
            T[rr][k] = v;
        }
        SD[rr][kq] = s; AD[rr][kq] = a;
        __syncthreads();
        if (tid < 64) {
            double ss = SD[tid][0] + SD[tid][1] + SD[tid][2] + SD[tid][3];
            double aa = AD[tid][0] + AD[tid][1] + AD[tid][2] + AD[tid][3];
            S[r0 + tid] = (float)ss;
            MARG[r0 + tid] = 1.2e-4f + 6.5e-7f * (float)aa;
        }
        const int m = tid >> 2, koff = (tid & 3) * 64;
#pragma unroll
        for (int c = 0; c < 8; ++c) {
            unsigned short us[8];
#pragma unroll
            for (int j = 0; j < 8; ++j) us[j] = to_fp16_bits(T[m][koff + c * 8 + j]);
            *(uint4*)(zfh + (size_t)(r0 + m) * 256 + koff + c * 8) = *(uint4*)us;
        }
    } else {
        const int eb = blk - 256;
        const float* src = emb + (size_t)eb * 16384;
        unsigned short* dst = efh + (size_t)eb * 16384;
#pragma unroll
        for (int it = 0; it < 16; ++it) {
            int e4 = tid + it * 256;
            float4 v = ((const float4*)src)[e4];
            unsigned short us[4] = {to_fp16_bits(v.x * ESCALE), to_fp16_bits(v.y * ESCALE),
                                    to_fp16_bits(v.z * ESCALE), to_fp16_bits(v.w * ESCALE)};
            *(uint2*)(dst + (size_t)e4 * 4) = *(uint2*)us;
        }
        const int n0 = eb * 64;
        const int rr = tid & 63, kq = tid >> 6;
        const float* p = emb + (size_t)(n0 + rr) * 256 + kq * 64;
        double s = 0.0;
#pragma unroll 8
        for (int kk = 0; kk < 64; ++kk) { float v = p[kk]; s += (double)v * (double)v; }
        SD[rr][kq] = s;
        __syncthreads();
        if (tid < 64)
            E[n0 + tid] = (float)(SD[tid][0] + SD[tid][1] + SD[tid][2] + SD[tid][3]);
    }
}

// =======================================================================
// k_gemm v4 (R17): MFMA core, LDS layout, ds_read side, epilogue, CH
// values — all byte-identical to the R16-passing version. ONLY the
// global->LDS staging path changed: reg-roundtrip (global_load -> VGPR ->
// ds_write; 64 wave-instrs/kt) replaced by global_load_lds width=16
// (8 wave-instrs/kt). Source address pre-swizzled so the LINEAR LDS dest
// reproduces the swizzled layout bit-for-bit:
//   1KB segment = 8 rows (m = seg*8 + (l>>3)); lane l writes slot l&7 of
//   row m; choosing source c = (l&7)^(l>>3) gives slot s holding column
//   c = s^(m&7) — exactly today's write As[m*64 + ((c^(m&7))<<3)].
// (R16 counters: k_gemm 124us, MfmaUtil 24%, VALUBusy 33%, FETCH 20MB ->
//  staging-issue-bound; guide ladder m93->m97 shows width-16 gload_lds is
//  the proven fix for exactly this signature.)
// =======================================================================
__global__ __launch_bounds__(256) void k_gemm(
    const unsigned short* __restrict__ zfh, const unsigned short* __restrict__ efh,
    const float* __restrict__ S, const float* __restrict__ E,
    _Float16* __restrict__ CH) {
    __shared__ __align__(16) unsigned short As[128 * 64];
    __shared__ __align__(16) unsigned short Bs[128 * 64];

    const int tid = threadIdx.x;
    const int lane = tid & 63, wave = tid >> 6;
    const int wm = (wave & 1) * 64, wn = (wave >> 1) * 64;
    const int row0 = blockIdx.x * 128, col0 = blockIdx.y * 128;
    const int lm = lane & 15, lq = lane >> 4;

    v4f acc[4][4];
#pragma unroll
    for (int i = 0; i < 4; ++i)
#pragma unroll
        for (int j = 0; j < 4; ++j) acc[i][j] = (v4f){0.f, 0.f, 0.f, 0.f};

    const int mrow = lane >> 3;                // 0..7 within segment
    const int csrc = (lane & 7) ^ mrow;        // pre-swizzled source slot

    for (int kt = 0; kt < 4; ++kt) {
        const int kbase = kt * 64;
#pragma unroll
        for (int t = 0; t < 4; ++t) {
            const int seg = wave * 4 + t;      // 0..15, 8 rows each
            const int m = seg * 8 + mrow;
            gl_lds16(zfh + (size_t)(row0 + m) * 256 + kbase + csrc * 8,
                     As + seg * 512);
            gl_lds16(efh + (size_t)(col0 + m) * 256 + kbase + csrc * 8,
                     Bs + seg * 512);
        }
        __syncthreads();
#pragma unroll
        for (int s = 0; s < 2; ++s) {
            v8h af[4], bfr[4];
#pragma unroll
            for (int fi = 0; fi < 4; ++fi) {
                int m = wm + fi * 16 + lm;
                int c = (s << 2) | lq;
                af[fi] = *(const v8h*)(As + m * 64 + ((c ^ (m & 7)) << 3));
            }
#pragma unroll
            for (int fj = 0; fj < 4; ++fj) {
                int n = wn + fj * 16 + lm;
                int c = (s << 2) | lq;
                bfr[fj] = *(const v8h*)(Bs + n * 64 + ((c ^ (n & 7)) << 3));
            }
#pragma unroll
            for (int fi = 0; fi < 4; ++fi)
#pragma unroll
                for (int fj = 0; fj < 4; ++fj)
                    acc[fi][fj] = __builtin_amdgcn_mfma_f32_16x16x32_f16(
                        af[fi], bfr[fj], acc[fi][fj], 0, 0, 0);
        }
        __syncthreads();
    }

    float Sl[16];
#pragma unroll
    for (int fi = 0; fi < 4; ++fi)
#pragma unroll
        for (int r = 0; r < 4; ++r)
            Sl[fi * 4 + r] = S[row0 + wm + fi * 16 + lq * 4 + r];
    float En[4];
#pragma unroll
    for (int fj = 0; fj < 4; ++fj) En[fj] = E[col0 + wn + fj * 16 + lm];

    float dmin[16];
#pragma unroll
    for (int fi = 0; fi < 4; ++fi)
#pragma unroll
        for (int r = 0; r < 4; ++r) {
            float dm = __builtin_inff();
#pragma unroll
            for (int fj = 0; fj < 4; ++fj) {
                float d = (Sl[fi * 4 + r] + En[fj]) - acc[fi][fj][r] * DESCALE;
                dm = fminf(dm, d);
            }
            dmin[fi * 4 + r] = dm;
        }
#pragma unroll
    for (int msk = 1; msk < 16; msk <<= 1)
#pragma unroll
        for (int i = 0; i < 16; ++i)
            dmin[i] = fminf(dmin[i], __shfl_xor(dmin[i], msk, 64));

    if (lm == 0) {
        const int cb = blockIdx.y * 2 + (wn >> 6);
#pragma unroll
        for (int i = 0; i < 16; ++i) {
            int fi = i >> 2, r = i & 3;
            int gm = row0 + wm + fi * 16 + lq * 4 + r;
            float rel = dmin[i] - Sl[i];             // Sterbenz: exact
            CH[(size_t)gm * 128 + cb] = (_Float16)rel;
        }
    }
}

// =======================================================================
// k_rescore v11 (R16-PASSING, byte-identical): cooperative-coalesced
// refine (8 lanes/col x 8 cols/pass, butterfly sums, fixed source-side
// redistribution), R0 candidate/survivor logic verbatim, byte-identical
// exact fp32 chain, key=(d-bits,js) min. absmax 0.0 verified.
// =======================================================================
__global__ __launch_bounds__(1024) void k_rescore(
    const float* __restrict__ z, const float* __restrict__ emb,
    const float* __restrict__ S, const float* __restrict__ E,
    const float* __restrict__ MARG,
    const unsigned short* __restrict__ zfh,
    const unsigned short* __restrict__ efh,
    const _Float16* __restrict__ CH,
    int* __restrict__ IDX, float* __restrict__ idx_f) {
    __shared__ float zs[32][260];
    __shared__ uint4 zh4[32][32];              // 32 rows of zfh (fp16 pairs)
    const int tid = threadIdx.x;
    const int r0 = blockIdx.x * 32;            // 32 consecutive rows, same b
    const int b = r0 >> 10, hw0 = r0 & 1023;
    const float* zb = z + ((size_t)b << 18) + hw0;

    // stage 32x256 fp32 z: float4 over hw (full 128B lines, coalesced) — R0
#pragma unroll
    for (int it = 0; it < 2; ++it) {
        int slot = tid + it * 1024;            // 0..2047 float4 slots
        int c = slot >> 3, h4 = (slot & 7) << 2;
        float4 v = *(const float4*)(zb + (size_t)c * 1024 + h4);
        zs[h4 + 0][c] = v.x; zs[h4 + 1][c] = v.y;
        zs[h4 + 2][c] = v.z; zs[h4 + 3][c] = v.w;
    }
    // stage 32 zfh rows (16KB, coalesced)
    {
        int rr = tid >> 5, q = tid & 31;
        zh4[rr][q] = ((const uint4*)(zfh + (size_t)(r0 + rr) * 256))[q];
    }
    __syncthreads();

    const int lane = tid & 63, wave = tid >> 6;   // 16 waves
    const int gid = lane >> 3, lg = lane & 7;     // col-group / lane-in-group
#pragma unroll
    for (int rw = 0; rw < 2; ++rw) {
        const int rl = wave * 2 + rw;
        const int r = r0 + rl;

        float m0 = (float)CH[(size_t)r * 128 + lane];
        float m1 = (float)CH[(size_t)r * 128 + 64 + lane];
        float g = fminf(m0, m1);
#pragma unroll
        for (int off = 32; off; off >>= 1) g = fminf(g, __shfl_xor(g, off, 64));
        const float thr = g + MARG[r];
        const float MB  = 0.75f * MARG[r];
        const float Sr = S[r];

        unsigned long long p0 = __ballot(m0 <= thr);
        unsigned long long p1 = __ballot(m1 <= thr);

        unsigned long long key = ~0ull;
        float grun = __builtin_inff();
        for (int half = 0; half < 2; ++half) {
            unsigned long long pm = half ? p1 : p0;
            while (pm) {                       // wave-uniform, ascending chunks
                int c = __ffsll((long long)pm) - 1; pm &= pm - 1;
                const int cb = half * 64 + c;
                const int j0 = cb << 6;
                // ---- cooperative coalesced refine: 8 passes x 8 cols;
                // 8 lanes/col, each covering 4x(8 dims) at stride 64
                float dP[8];
#pragma unroll
                for (int p = 0; p < 8; ++p) {
                    const int j = j0 + p * 8 + gid;
                    const uint4* ep = (const uint4*)(efh + ((size_t)j << 8));
                    float a0 = 0.0f, a1 = 0.0f;
#pragma unroll
                    for (int q = 0; q < 4; ++q) {
                        uint4 ev = ep[q * 8 + lg];       // dims (q*8+lg)*8..+7
                        uint4 zv = zh4[rl][q * 8 + lg];  // same dims of z
                        a0 = dot2f(h2bc(zv.x), h2bc(ev.x), a0);
                        a1 = dot2f(h2bc(zv.y), h2bc(ev.y), a1);
                        a0 = dot2f(h2bc(zv.z), h2bc(ev.z), a0);
                        a1 = dot2f(h2bc(zv.w), h2bc(ev.w), a1);
                    }
                    float acc = a0 + a1;
                    // butterfly over the 8-lane group: commutative adds ->
                    // identical bits on all 8 lanes (deterministic)
                    acc += __shfl_xor(acc, 1, 64);
                    acc += __shfl_xor(acc, 2, 64);
                    acc += __shfl_xor(acc, 4, 64);
                    dP[p] = (Sr + E[j]) - acc * DESCALE;
                }
                // redistribute: source lane selects by ITS OWN lg; dest d
                // reads source ((d&7)<<3)|(d>>3) which holds dP[d>>3] of
                // group d&7 = col j0+d. (R16 fix, verified passing.)
                float sel = dP[0];
                sel = (lg == 1) ? dP[1] : sel;
                sel = (lg == 2) ? dP[2] : sel;
                sel = (lg == 3) ? dP[3] : sel;
                sel = (lg == 4) ? dP[4] : sel;
                sel = (lg == 5) ? dP[5] : sel;
                sel = (lg == 6) ? dP[6] : sel;
                sel = (lg == 7) ? dP[7] : sel;
                float dref = __shfl(sel, ((lane & 7) << 3) | (lane >> 3), 64);
                // ---- R0 survivor logic verbatim
                float lmin = dref;
#pragma unroll
                for (int off = 32; off; off >>= 1)
                    lmin = fminf(lmin, __shfl_xor(lmin, off, 64));
                grun = fminf(grun, lmin);
                // superset-safe: stale-high grun only adds survivors
                unsigned long long sm = __ballot(dref <= grun + MB);
                while (sm) {                   // ~1.2 survivors/row, ascending
                    int s = __ffsll((long long)sm) - 1; sm &= sm - 1;
                    const int js = (cb << 6) | s;
                    // ---- exact fp32 chain (bit-identical): LDS-broadcast z,
                    // broadcast emb row, ascending k
                    const float4* ep4 = (const float4*)(emb + ((size_t)js << 8));
                    float m = 0.0f;
#pragma unroll 8
                    for (int k4 = 0; k4 < 64; ++k4) {
                        float4 e4 = ep4[k4];
                        m = fmaf(zs[rl][k4 * 4 + 0], e4.x, m);
                        m = fmaf(zs[rl][k4 * 4 + 1], e4.y, m);
                        m = fmaf(zs[rl][k4 * 4 + 2], e4.z, m);
                        m = fmaf(zs[rl][k4 * 4 + 3], e4.w, m);
                    }
                    float d = (Sr + E[js]) - 2.0f * m;   // d>0 -> bits monotone
                    unsigned long long kk =
                        ((unsigned long long)__float_as_uint(d) << 32) | (unsigned)js;
                    key = kk < key ? kk : key; // lane-uniform
                }
            }
        }
        if (lane == 0) {
            int j = (int)(key & 0xFFFFFFFFull);
            IDX[r] = j;
            idx_f[r] = (float)j;
        }
    }
}

// =======================================================================
// k_out v2 (validated R8/R9, unchanged) + k_fin (deterministic loss)
// =======================================================================
__global__ __launch_bounds__(256) void k_out(const float* __restrict__ z,
                                             const float* __restrict__ emb,
                                             const int* __restrict__ idx,
                                             float* __restrict__ out,
                                             float* __restrict__ lossp) {
    __shared__ __align__(16) float EB[32 * 260];
    __shared__ float red[256];
    __shared__ int ids[32];
    const int tid = threadIdx.x;
    const int r0 = blockIdx.x * 32;            // 32 consecutive rows, same b
    const int b = r0 >> 10, hw0 = r0 & 1023;

    if (tid < 32) ids[tid] = idx[r0 + tid];
    __syncthreads();
#pragma unroll
    for (int it = 0; it < 8; ++it) {
        int i = tid + it * 256;                // 0..2047
        int rr = i >> 6, k4 = i & 63;
        float4 v = *(const float4*)(emb + (size_t)ids[rr] * 256 + k4 * 4);
        *(float4*)(EB + rr * 260 + k4 * 4) = v;
    }
    __syncthreads();

    const float* zb = z + ((size_t)b << 18) + hw0;
    float*       ob = out + ((size_t)b << 18) + hw0;
    const int hq = tid & 7;
    const int cg = tid >> 3;
    float lsum = 0.0f;
#pragma unroll
    for (int it = 0; it < 8; ++it) {
        int c = it * 32 + cg;
        float4 zv = *(const float4*)(zb + (size_t)c * 1024 + hq * 4);
        float e0 = EB[(hq * 4 + 0) * 260 + c];
        float e1 = EB[(hq * 4 + 1) * 260 + c];
        float e2 = EB[(hq * 4 + 2) * 260 + c];
        float e3 = EB[(hq * 4 + 3) * 260 + c];
        float d0 = e0 - zv.x, d1 = e1 - zv.y, d2 = e2 - zv.z, d3 = e3 - zv.w;
        float4 ov = {zv.x + d0, zv.y + d1, zv.z + d2, zv.w + d3};
        *(float4*)(ob + (size_t)c * 1024 + hq * 4) = ov;
        lsum += d0 * d0 + d1 * d1 + d2 * d2 + d3 * d3;
    }
    red[tid] = lsum;
    __syncthreads();
    for (int off = 128; off; off >>= 1) {
        if (tid < off) red[tid] += red[tid + off];
        __syncthreads();
    }
    if (tid == 0) lossp[blockIdx.x] = red[0];
}

__global__ __launch_bounds__(256) void k_fin(const float* __restrict__ lossp,
                                             float* __restrict__ out_loss) {
    __shared__ float red[256];
    const int tid = threadIdx.x;
    red[tid] = lossp[tid] + lossp[tid + 256];
    __syncthreads();
    for (int off = 128; off; off >>= 1) {
        if (tid < off) red[tid] += red[tid + off];
        __syncthreads();
    }
    if (tid == 0) {
        float m = red[0] / 4194304.0f;
        out_loss[0] = m + 0.25f * m;
    }
}

// =======================================================================
// Fallback path (round-2 core, proven): used only if ws is too small.
// =======================================================================
#define FWS_S     0
#define FWS_E     (FWS_S + NROWS)
#define FWS_KEY   (FWS_E + NE)
#define FWS_IDX   (FWS_KEY + NROWS * 2)
#define FWS_LOSSP (FWS_IDX + NROWS)

__global__ void f_rowsum_z(const float* __restrict__ z, float* __restrict__ S) {
    int r = blockIdx.x * 256 + threadIdx.x;
    int b = r >> 10, hw = r & 1023;
    const float* p = z + (size_t)b * 262144 + hw;
    double s = 0.0;
#pragma unroll 8
    for (int c = 0; c < 256; ++c) { float v = p[(size_t)c * 1024]; s += (double)v * (double)v; }
    S[r] = (float)s;
}
__global__ void f_rowsum_e(const float* __restrict__ emb, float* __restrict__ E) {
    int row = blockIdx.x * 4 + (threadIdx.x >> 6);
    int lane = threadIdx.x & 63;
    const float* p = emb + (size_t)row * 256;
    double s = 0.0;
#pragma unroll
    for (int i = 0; i < 4; ++i) { float v = p[lane + i * 64]; s += (double)v * (double)v; }
    for (int off = 32; off; off >>= 1) s += __shfl_down(s, off, 64);
    if (lane == 0) E[row] = (float)s;
}
__global__ __launch_bounds__(256, 4) void f_gemm_argmin(
    const float* __restrict__ z, const float* __restrict__ emb,
    const float* __restrict__ S, const float* __restrict__ E,
    unsigned long long* __restrict__ keys) {
    __shared__ __align__(16) float As[32][128];
    __shared__ __align__(16) float Bs[32][133];
    const int tid = threadIdx.x;
    const int tx = tid & 15, ty = tid >> 4;
    const int row0 = blockIdx.x * 128, col0 = blockIdx.y * 128;
    const int b = row0 >> 10, hw0 = row0 & 1023;
    const float* zb = z + (size_t)b * 262144 + hw0;
    float acc[8][8];
#pragma unroll
    for (int i = 0; i < 8; ++i)
#pragma unroll
        for (int j = 0; j < 8; ++j) acc[i][j] = 0.0f;
    for (int kt = 0; kt < 8; ++kt) {
        const int kbase = kt * 32;
#pragma unroll
        for (int it = 0; it < 4; ++it) {
            int e = tid + it * 256;
            int k = e >> 5, m4 = (e & 31) << 2;
            *(float4*)&As[k][m4] = *(const float4*)(zb + (size_t)(kbase + k) * 1024 + m4);
        }
#pragma unroll
        for (int it = 0; it < 4; ++it) {
            int e = tid + it * 256;
            int n = e >> 3, k4 = (e & 7) << 2;
            float4 v = *(const float4*)(emb + (size_t)(col0 + n) * 256 + kbase + k4);
            Bs[k4 + 0][n] = v.x; Bs[k4 + 1][n] = v.y;
            Bs[k4 + 2][n] = v.z; Bs[k4 + 3][n] = v.w;
        }
        __syncthreads();
#pragma unroll 8
        for (int k = 0; k < 32; ++k) {
            float4 a0 = *(const float4*)&As[k][tx * 4];
            float4 a1 = *(const float4*)&As[k][64 + tx * 4];
            float4 b0 = *(const float4*)&Bs[k][ty * 4];
            float4 b1 = *(const float4*)&Bs[k][64 + ty * 4];
            float a_[8] = {a0.x, a0.y, a0.z, a0.w, a1.x, a1.y, a1.z, a1.w};
            float b_[8] = {b0.x, b0.y, b0.z, b0.w, b1.x, b1.y, b1.z, b1.w};
#pragma unroll
            for (int i = 0; i < 8; ++i)
#pragma unroll
                for (int j = 0; j < 8; ++j) acc[i][j] += a_[i] * b_[j];
        }
        __syncthreads();
    }
    float4 S0 = *(const float4*)(S + row0 + tx * 4);
    float4 S1 = *(const float4*)(S + row0 + 64 + tx * 4);
    float4 E0 = *(const float4*)(E + col0 + ty * 4);
    float4 E1 = *(const float4*)(E + col0 + 64 + ty * 4);
    float Sr[8] = {S0.x, S0.y, S0.z, S0.w, S1.x, S1.y, S1.z, S1.w};
    float Ec[8] = {E0.x, E0.y, E0.z, E0.w, E1.x, E1.y, E1.z, E1.w};
    unsigned long long best[8];
#pragma unroll
    for (int i = 0; i < 8; ++i) best[i] = ~0ull;
#pragma unroll
    for (int j = 0; j < 8; ++j) {
        int col = col0 + ((j < 4) ? (ty * 4 + j) : (64 + ty * 4 + j - 4));
#pragma unroll
        for (int i = 0; i < 8; ++i) {
            float t = Sr[i] + Ec[j];
            float d = t - 2.0f * acc[i][j];
            unsigned ud = __float_as_uint(d);
            ud = (ud & 0x80000000u) ? ~ud : (ud | 0x80000000u);
            unsigned long long key = ((unsigned long long)ud << 32) | (unsigned)col;
            if (key < best[i]) best[i] = key;
        }
    }
    __syncthreads();
    unsigned long long* Sk = (unsigned long long*)&As[0][0];
#pragma unroll
    for (int i = 0; i < 4; ++i) {
        Sk[ty * 128 + tx * 4 + i] = best[i];
        Sk[ty * 128 + 64 + tx * 4 + i] = best[4 + i];
    }
    __syncthreads();
    if (tid < 128) {
        unsigned long long m = ~0ull;
#pragma unroll
        for (int t = 0; t < 16; ++t) {
            unsigned long long v = Sk[t * 128 + tid];
            m = v < m ? v : m;
        }
        atomicMin(&keys[row0 + tid], m);
    }
}
__global__ void f_merge(const unsigned long long* __restrict__ keys,
                        int* __restrict__ idx, float* __restrict__ idx_f) {
    int r = blockIdx.x * 256 + threadIdx.x;
    int bestj = (int)(keys[r] & 0xFFFFFFFFull);
    idx[r] = bestj;
    idx_f[r] = (float)bestj;
}

extern "C" void kernel_launch(void* const* d_in, const int* in_sizes, int n_in,
                              void* d_out, int out_size, void* d_ws, size_t ws_size,
                              hipStream_t stream) {
    const float* z   = (const float*)d_in[0];
    const float* emb = (const float*)d_in[1];
    float* out = (float*)d_out;
    float* ws  = (float*)d_ws;

    if (ws_size >= (size_t)WS_NEED_FLOATS * 4) {
        float* S = ws + OFF_S;
        float* E = ws + OFF_E;
        float* MARG = ws + OFF_MARG;
        int* IDX = (int*)(ws + OFF_IDX);
        _Float16* CH = (_Float16*)(ws + OFF_CH);
        unsigned short* ZFH = (unsigned short*)(ws + OFF_ZFH);
        unsigned short* EFH = (unsigned short*)(ws + OFF_EFH);
        float* LOSSP = ws + OFF_LOSSP;

        k_pre<<<384, 256, 0, stream>>>(z, emb, ws);
        dim3 g(NROWS / 128, NE / 128);
        k_gemm<<<g, 256, 0, stream>>>(ZFH, EFH, S, E, CH);
        k_rescore<<<NROWS / 32, 1024, 0, stream>>>(z, emb, S, E, MARG, ZFH, EFH,
                                                   CH, IDX, out + OUT_N + 1);
        k_out<<<NROWS / 32, 256, 0, stream>>>(z, emb, IDX, out, LOSSP);
        k_fin<<<1, 256, 0, stream>>>(LOSSP, out + OUT_N);
    } else {
        float* S = ws + FWS_S;
        float* E = ws + FWS_E;
        unsigned long long* KEYS = (unsigned long long*)(ws + FWS_KEY);
        int* IDX = (int*)(ws + FWS_IDX);
        float* LOSSP = ws + FWS_LOSSP;

        f_rowsum_z<<<NROWS / 256, 256, 0, stream>>>(z, S);
        f_rowsum_e<<<NE / 4, 256, 0, stream>>>(emb, E);
        hipMemsetAsync(KEYS, 0xFF, NROWS * sizeof(unsigned long long), stream);
        dim3 g(NROWS / 128, NE / 128);
        f_gemm_argmin<<<g, 256, 0, stream>>>(z, emb, S, E, KEYS);
        f_merge<<<NROWS / 256, 256, 0, stream>>>(KEYS, IDX, out + OUT_N + 1);
        k_out<<<NROWS / 32, 256, 0, stream>>>(z, emb, IDX, out, LOSSP);
        k_fin<<<1, 256, 0, stream>>>(LOSSP, out + OUT_N);
    }
}

// Round 9
// 272.935 us; speedup vs baseline: 2.2328x; 1.0258x over previous
//
#include <hip/hip_runtime.h>
#include <hip/hip_bf16.h>

#define NROWS 16384      // 16*32*32
#define EDIM  256
#define NE    8192
#define OUT_N 4194304    // 16*256*32*32

typedef _Float16 v8h __attribute__((ext_vector_type(8)));
typedef _Float16 v4h __attribute__((ext_vector_type(4)));
typedef _Float16 h2  __attribute__((ext_vector_type(2)));
typedef float    v4f __attribute__((ext_vector_type(4)));

// ---- main-path ws layout (float units) ---- (16.2 MB < 17.1 MB proven)
#define OFF_S     0                        // 16384
#define OFF_E     16384                    // 8192
#define OFF_MARG  24576                    // 16384
#define OFF_IDX   40960                    // 16384 i32
#define OFF_CH    57600                    // 16384*128 fp16 = 1048576 float slots
#define OFF_ZFH   1106176                  // 16384*256 fp16 = 2097152 float slots
#define OFF_EFH   3203328                  // 8192*256 fp16 = 1048576 float slots
#define OFF_LOSSP 4251904                  // 512 block partials
#define WS_NEED_FLOATS 4252416

#define ESCALE   1048576.0f                // 2^20 (exact); descale 2^-19 on d
#define DESCALE  0x1p-19f

static __device__ __forceinline__ unsigned short to_fp16_bits(float v) {
    _Float16 h = (_Float16)v;
    return __builtin_bit_cast(unsigned short, h);
}

static __device__ __forceinline__ h2 h2bc(unsigned int u) {
    return __builtin_bit_cast(h2, u);
}

// async global->LDS, 16B per lane (wave-uniform LDS base + lane*16; global
// source per-lane). Guide §5: width=16 is the m97 staging path.
static __device__ __forceinline__ void gl_lds16(const void* g, void* l) {
    __builtin_amdgcn_global_load_lds(
        (const __attribute__((address_space(1))) unsigned int*)g,
        (__attribute__((address_space(3))) unsigned int*)l, 16, 0, 0);
}

// fp16x2 dot with fp32 accumulate (validated in R16 passing run: exact fp16
// inputs, fp32 accumulate — same error class as the R7/R8 refine bound).
static __device__ __forceinline__ float dot2f(h2 a, h2 b, float c) {
#if defined(__has_builtin)
#if __has_builtin(__builtin_amdgcn_fdot2)
    return __builtin_amdgcn_fdot2(a, b, c, false);
#else
    return fmaf((float)a.y, (float)b.y, fmaf((float)a.x, (float)b.x, c));
#endif
#else
    return fmaf((float)a.y, (float)b.y, fmaf((float)a.x, (float)b.x, c));
#endif
}

// =======================================================================
// k_pre (validated R6-R9, byte-identical to R0-passing version):
// z rows (S, MARG, z cvt fp16), emb (cvt*2^20 + E sums).
// =======================================================================
__global__ __launch_bounds__(256) void k_pre(const float* __restrict__ z,
                                             const float* __restrict__ emb,
                                             float* __restrict__ ws) {
    float* S = ws + OFF_S;
    float* E = ws + OFF_E;
    float* MARG = ws + OFF_MARG;
    unsigned short* zfh = (unsigned short*)(ws + OFF_ZFH);
    unsigned short* efh = (unsigned short*)(ws + OFF_EFH);

    const int blk = blockIdx.x, tid = threadIdx.x;

    __shared__ float T[64][260];
    __shared__ double SD[64][4];
    __shared__ double AD[64][4];

    if (blk < 256) {
        const int r0 = blk * 64;
        const int b = r0 >> 10, hw0 = r0 & 1023;   // 64-row tile never crosses b
        const int rr = tid & 63, kq = tid >> 6;
        const float* zp = z + (size_t)b * 262144 + hw0 + rr;
        double s = 0.0, a = 0.0;
#pragma unroll 8
        for (int kk = 0; kk < 64; ++kk) {
            int k = kq * 64 + kk;
            float v = zp[(size_t)k << 10];
            s += (double)v * (double)v;
            a += fabs((double)v);
            T[rr][k] = v;
        }
        SD[rr][kq] = s; AD[rr][kq] = a;
        __syncthreads();
        if (tid < 64) {
            double ss = SD[tid][0] + SD[tid][1] + SD[tid][2] + SD[tid][3];
            double aa = AD[tid][0] + AD[tid][1] + AD[tid][2] + AD[tid][3];
            S[r0 + tid] = (float)ss;
            MARG[r0 + tid] = 1.2e-4f + 6.5e-7f * (float)aa;
        }
        const int m = tid >> 2, koff = (tid & 3) * 64;
#pragma unroll
        for (int c = 0; c < 8; ++c) {
            unsigned short us[8];
#pragma unroll
            for (int j = 0; j < 8; ++j) us[j] = to_fp16_bits(T[m][koff + c * 8 + j]);
            *(uint4*)(zfh + (size_t)(r0 + m) * 256 + koff + c * 8) = *(uint4*)us;
        }
    } else {
        const int eb = blk - 256;
        const float* src = emb + (size_t)eb * 16384;
        unsigned short* dst = efh + (size_t)eb * 16384;
#pragma unroll
        for (int it = 0; it < 16; ++it) {
            int e4 = tid + it * 256;
            float4 v = ((const float4*)src)[e4];
            unsigned short us[4] = {to_fp16_bits(v.x * ESCALE), to_fp16_bits(v.y * ESCALE),
                                    to_fp16_bits(v.z * ESCALE), to_fp16_bits(v.w * ESCALE)};
            *(uint2*)(dst + (size_t)e4 * 4) = *(uint2*)us;
        }
        const int n0 = eb * 64;
        const int rr = tid & 63, kq = tid >> 6;
        const float* p = emb + (size_t)(n0 + rr) * 256 + kq * 64;
        double s = 0.0;
#pragma unroll 8
        for (int kk = 0; kk < 64; ++kk) { float v = p[kk]; s += (double)v * (double)v; }
        SD[rr][kq] = s;
        __syncthreads();
        if (tid < 64)
            E[n0 + tid] = (float)(SD[tid][0] + SD[tid][1] + SD[tid][2] + SD[tid][3]);
    }
}

// =======================================================================
// k_gemm v5 (R18): 256x256 tile, 512 thr (8 waves = 2M x 4N; per-wave
// 128x64 sub-tile whose 64 cols = exactly one CH chunk). Rationale (R17
// counters): MfmaUtil 28% at 128^2 because tiny K (4 kt steps) leaves
// staging+epilogue unamortized; 256^2 doubles MFMA per staged byte.
// VALUE-PRESERVING: same 16x16x32 MFMA, same ascending kt(4) x s(2)
// accumulation per (row,col) -> acc bits identical; same chunk-min fminf
// tree (fj 0..3 then shfl merge msk 1..8 over lm) -> CH bit-identical.
// Staging: same 1KB-segment gl_lds width-16 with pre-swizzled source
// (slot (l&7)^(l>>3)), 32 segments per matrix. LDS 64KB (As+Bs).
// =======================================================================
__global__ __launch_bounds__(512) void k_gemm(
    const unsigned short* __restrict__ zfh, const unsigned short* __restrict__ efh,
    const float* __restrict__ S, const float* __restrict__ E,
    _Float16* __restrict__ CH) {
    __shared__ __align__(16) unsigned short As[256 * 64];
    __shared__ __align__(16) unsigned short Bs[256 * 64];

    const int tid = threadIdx.x;
    const int lane = tid & 63, wave = tid >> 6;       // 8 waves: 2M x 4N
    const int wm = (wave >> 2) * 128, wn = (wave & 3) * 64;
    const int row0 = blockIdx.x * 256, col0 = blockIdx.y * 256;
    const int lm = lane & 15, lq = lane >> 4;

    v4f acc[8][4];
#pragma unroll
    for (int i = 0; i < 8; ++i)
#pragma unroll
        for (int j = 0; j < 4; ++j) acc[i][j] = (v4f){0.f, 0.f, 0.f, 0.f};

    const int mrow = lane >> 3;                // 0..7 within segment
    const int csrc = (lane & 7) ^ mrow;        // pre-swizzled source slot

    for (int kt = 0; kt < 4; ++kt) {
        const int kbase = kt * 64;
#pragma unroll
        for (int t = 0; t < 4; ++t) {
            const int seg = wave * 4 + t;      // 0..31, 8 rows each
            const int m = seg * 8 + mrow;      // 0..255
            gl_lds16(zfh + (size_t)(row0 + m) * 256 + kbase + csrc * 8,
                     As + seg * 512);
            gl_lds16(efh + (size_t)(col0 + m) * 256 + kbase + csrc * 8,
                     Bs + seg * 512);
        }
        __syncthreads();
#pragma unroll
        for (int s = 0; s < 2; ++s) {
            v8h af[8], bfr[4];
#pragma unroll
            for (int fi = 0; fi < 8; ++fi) {
                int m = wm + fi * 16 + lm;
                int c = (s << 2) | lq;
                af[fi] = *(const v8h*)(As + m * 64 + ((c ^ (m & 7)) << 3));
            }
#pragma unroll
            for (int fj = 0; fj < 4; ++fj) {
                int n = wn + fj * 16 + lm;
                int c = (s << 2) | lq;
                bfr[fj] = *(const v8h*)(Bs + n * 64 + ((c ^ (n & 7)) << 3));
            }
#pragma unroll
            for (int fi = 0; fi < 8; ++fi)
#pragma unroll
                for (int fj = 0; fj < 4; ++fj)
                    acc[fi][fj] = __builtin_amdgcn_mfma_f32_16x16x32_f16(
                        af[fi], bfr[fj], acc[fi][fj], 0, 0, 0);
        }
        __syncthreads();
    }

    float Sl[32];
#pragma unroll
    for (int fi = 0; fi < 8; ++fi)
#pragma unroll
        for (int r = 0; r < 4; ++r)
            Sl[fi * 4 + r] = S[row0 + wm + fi * 16 + lq * 4 + r];
    float En[4];
#pragma unroll
    for (int fj = 0; fj < 4; ++fj) En[fj] = E[col0 + wn + fj * 16 + lm];

    float dmin[32];
#pragma unroll
    for (int fi = 0; fi < 8; ++fi)
#pragma unroll
        for (int r = 0; r < 4; ++r) {
            float dm = __builtin_inff();
#pragma unroll
            for (int fj = 0; fj < 4; ++fj) {
                float d = (Sl[fi * 4 + r] + En[fj]) - acc[fi][fj][r] * DESCALE;
                dm = fminf(dm, d);
            }
            dmin[fi * 4 + r] = dm;
        }
#pragma unroll
    for (int msk = 1; msk < 16; msk <<= 1)
#pragma unroll
        for (int i = 0; i < 32; ++i)
            dmin[i] = fminf(dmin[i], __shfl_xor(dmin[i], msk, 64));

    if (lm == 0) {
        const int cb = blockIdx.y * 4 + (wn >> 6);
#pragma unroll
        for (int i = 0; i < 32; ++i) {
            int fi = i >> 2, r = i & 3;
            int gm = row0 + wm + fi * 16 + lq * 4 + r;
            float rel = dmin[i] - Sl[i];             // Sterbenz: exact
            CH[(size_t)gm * 128 + cb] = (_Float16)rel;
        }
    }
}

// =======================================================================
// k_rescore v11 (R16/R17-PASSING, byte-identical): cooperative-coalesced
// refine (8 lanes/col x 8 cols/pass, butterfly sums, fixed source-side
// redistribution), R0 candidate/survivor logic verbatim, byte-identical
// exact fp32 chain, key=(d-bits,js) min. absmax 0.0 verified twice.
// =======================================================================
__global__ __launch_bounds__(1024) void k_rescore(
    const float* __restrict__ z, const float* __restrict__ emb,
    const float* __restrict__ S, const float* __restrict__ E,
    const float* __restrict__ MARG,
    const unsigned short* __restrict__ zfh,
    const unsigned short* __restrict__ efh,
    const _Float16* __restrict__ CH,
    int* __restrict__ IDX, float* __restrict__ idx_f) {
    __shared__ float zs[32][260];
    __shared__ uint4 zh4[32][32];              // 32 rows of zfh (fp16 pairs)
    const int tid = threadIdx.x;
    const int r0 = blockIdx.x * 32;            // 32 consecutive rows, same b
    const int b = r0 >> 10, hw0 = r0 & 1023;
    const float* zb = z + ((size_t)b << 18) + hw0;

    // stage 32x256 fp32 z: float4 over hw (full 128B lines, coalesced) — R0
#pragma unroll
    for (int it = 0; it < 2; ++it) {
        int slot = tid + it * 1024;            // 0..2047 float4 slots
        int c = slot >> 3, h4 = (slot & 7) << 2;
        float4 v = *(const float4*)(zb + (size_t)c * 1024 + h4);
        zs[h4 + 0][c] = v.x; zs[h4 + 1][c] = v.y;
        zs[h4 + 2][c] = v.z; zs[h4 + 3][c] = v.w;
    }
    // stage 32 zfh rows (16KB, coalesced)
    {
        int rr = tid >> 5, q = tid & 31;
        zh4[rr][q] = ((const uint4*)(zfh + (size_t)(r0 + rr) * 256))[q];
    }
    __syncthreads();

    const int lane = tid & 63, wave = tid >> 6;   // 16 waves
    const int gid = lane >> 3, lg = lane & 7;     // col-group / lane-in-group
#pragma unroll
    for (int rw = 0; rw < 2; ++rw) {
        const int rl = wave * 2 + rw;
        const int r = r0 + rl;

        float m0 = (float)CH[(size_t)r * 128 + lane];
        float m1 = (float)CH[(size_t)r * 128 + 64 + lane];
        float g = fminf(m0, m1);
#pragma unroll
        for (int off = 32; off; off >>= 1) g = fminf(g, __shfl_xor(g, off, 64));
        const float thr = g + MARG[r];
        const float MB  = 0.75f * MARG[r];
        const float Sr = S[r];

        unsigned long long p0 = __ballot(m0 <= thr);
        unsigned long long p1 = __ballot(m1 <= thr);

        unsigned long long key = ~0ull;
        float grun = __builtin_inff();
        for (int half = 0; half < 2; ++half) {
            unsigned long long pm = half ? p1 : p0;
            while (pm) {                       // wave-uniform, ascending chunks
                int c = __ffsll((long long)pm) - 1; pm &= pm - 1;
                const int cb = half * 64 + c;
                const int j0 = cb << 6;
                // ---- cooperative coalesced refine: 8 passes x 8 cols;
                // 8 lanes/col, each covering 4x(8 dims) at stride 64
                float dP[8];
#pragma unroll
                for (int p = 0; p < 8; ++p) {
                    const int j = j0 + p * 8 + gid;
                    const uint4* ep = (const uint4*)(efh + ((size_t)j << 8));
                    float a0 = 0.0f, a1 = 0.0f;
#pragma unroll
                    for (int q = 0; q < 4; ++q) {
                        uint4 ev = ep[q * 8 + lg];       // dims (q*8+lg)*8..+7
                        uint4 zv = zh4[rl][q * 8 + lg];  // same dims of z
                        a0 = dot2f(h2bc(zv.x), h2bc(ev.x), a0);
                        a1 = dot2f(h2bc(zv.y), h2bc(ev.y), a1);
                        a0 = dot2f(h2bc(zv.z), h2bc(ev.z), a0);
                        a1 = dot2f(h2bc(zv.w), h2bc(ev.w), a1);
                    }
                    float acc = a0 + a1;
                    // butterfly over the 8-lane group: commutative adds ->
                    // identical bits on all 8 lanes (deterministic)
                    acc += __shfl_xor(acc, 1, 64);
                    acc += __shfl_xor(acc, 2, 64);
                    acc += __shfl_xor(acc, 4, 64);
                    dP[p] = (Sr + E[j]) - acc * DESCALE;
                }
                // redistribute: source lane selects by ITS OWN lg; dest d
                // reads source ((d&7)<<3)|(d>>3) which holds dP[d>>3] of
                // group d&7 = col j0+d. (R16 fix, verified passing.)
                float sel = dP[0];
                sel = (lg == 1) ? dP[1] : sel;
                sel = (lg == 2) ? dP[2] : sel;
                sel = (lg == 3) ? dP[3] : sel;
                sel = (lg == 4) ? dP[4] : sel;
                sel = (lg == 5) ? dP[5] : sel;
                sel = (lg == 6) ? dP[6] : sel;
                sel = (lg == 7) ? dP[7] : sel;
                float dref = __shfl(sel, ((lane & 7) << 3) | (lane >> 3), 64);
                // ---- R0 survivor logic verbatim
                float lmin = dref;
#pragma unroll
                for (int off = 32; off; off >>= 1)
                    lmin = fminf(lmin, __shfl_xor(lmin, off, 64));
                grun = fminf(grun, lmin);
                // superset-safe: stale-high grun only adds survivors
                unsigned long long sm = __ballot(dref <= grun + MB);
                while (sm) {                   // ~1.2 survivors/row, ascending
                    int s = __ffsll((long long)sm) - 1; sm &= sm - 1;
                    const int js = (cb << 6) | s;
                    // ---- exact fp32 chain (bit-identical): LDS-broadcast z,
                    // broadcast emb row, ascending k
                    const float4* ep4 = (const float4*)(emb + ((size_t)js << 8));
                    float m = 0.0f;
#pragma unroll 8
                    for (int k4 = 0; k4 < 64; ++k4) {
                        float4 e4 = ep4[k4];
                        m = fmaf(zs[rl][k4 * 4 + 0], e4.x, m);
                        m = fmaf(zs[rl][k4 * 4 + 1], e4.y, m);
                        m = fmaf(zs[rl][k4 * 4 + 2], e4.z, m);
                        m = fmaf(zs[rl][k4 * 4 + 3], e4.w, m);
                    }
                    float d = (Sr + E[js]) - 2.0f * m;   // d>0 -> bits monotone
                    unsigned long long kk =
                        ((unsigned long long)__float_as_uint(d) << 32) | (unsigned)js;
                    key = kk < key ? kk : key; // lane-uniform
                }
            }
        }
        if (lane == 0) {
            int j = (int)(key & 0xFFFFFFFFull);
            IDX[r] = j;
            idx_f[r] = (float)j;
        }
    }
}

// =======================================================================
// k_out v2 (validated R8/R9, unchanged) + k_fin (deterministic loss)
// =======================================================================
__global__ __launch_bounds__(256) void k_out(const float* __restrict__ z,
                                             const float* __restrict__ emb,
                                             const int* __restrict__ idx,
                                             float* __restrict__ out,
                                             float* __restrict__ lossp) {
    __shared__ __align__(16) float EB[32 * 260];
    __shared__ float red[256];
    __shared__ int ids[32];
    const int tid = threadIdx.x;
    const int r0 = blockIdx.x * 32;            // 32 consecutive rows, same b
    const int b = r0 >> 10, hw0 = r0 & 1023;

    if (tid < 32) ids[tid] = idx[r0 + tid];
    __syncthreads();
#pragma unroll
    for (int it = 0; it < 8; ++it) {
        int i = tid + it * 256;                // 0..2047
        int rr = i >> 6, k4 = i & 63;
        float4 v = *(const float4*)(emb + (size_t)ids[rr] * 256 + k4 * 4);
        *(float4*)(EB + rr * 260 + k4 * 4) = v;
    }
    __syncthreads();

    const float* zb = z + ((size_t)b << 18) + hw0;
    float*       ob = out + ((size_t)b << 18) + hw0;
    const int hq = tid & 7;
    const int cg = tid >> 3;
    float lsum = 0.0f;
#pragma unroll
    for (int it = 0; it < 8; ++it) {
        int c = it * 32 + cg;
        float4 zv = *(const float4*)(zb + (size_t)c * 1024 + hq * 4);
        float e0 = EB[(hq * 4 + 0) * 260 + c];
        float e1 = EB[(hq * 4 + 1) * 260 + c];
        float e2 = EB[(hq * 4 + 2) * 260 + c];
        float e3 = EB[(hq * 4 + 3) * 260 + c];
        float d0 = e0 - zv.x, d1 = e1 - zv.y, d2 = e2 - zv.z, d3 = e3 - zv.w;
        float4 ov = {zv.x + d0, zv.y + d1, zv.z + d2, zv.w + d3};
        *(float4*)(ob + (size_t)c * 1024 + hq * 4) = ov;
        lsum += d0 * d0 + d1 * d1 + d2 * d2 + d3 * d3;
    }
    red[tid] = lsum;
    __syncthreads();
    for (int off = 128; off; off >>= 1) {
        if (tid < off) red[tid] += red[tid + off];
        __syncthreads();
    }
    if (tid == 0) lossp[blockIdx.x] = red[0];
}

__global__ __launch_bounds__(256) void k_fin(const float* __restrict__ lossp,
                                             float* __restrict__ out_loss) {
    __shared__ float red[256];
    const int tid = threadIdx.x;
    red[tid] = lossp[tid] + lossp[tid + 256];
    __syncthreads();
    for (int off = 128; off; off >>= 1) {
        if (tid < off) red[tid] += red[tid + off];
        __syncthreads();
    }
    if (tid == 0) {
        float m = red[0] / 4194304.0f;
        out_loss[0] = m + 0.25f * m;
    }
}

// =======================================================================
// Fallback path (round-2 core, proven): used only if ws is too small.
// =======================================================================
#define FWS_S     0
#define FWS_E     (FWS_S + NROWS)
#define FWS_KEY   (FWS_E + NE)
#define FWS_IDX   (FWS_KEY + NROWS * 2)
#define FWS_LOSSP (FWS_IDX + NROWS)

__global__ void f_rowsum_z(const float* __restrict__ z, float* __restrict__ S) {
    int r = blockIdx.x * 256 + threadIdx.x;
    int b = r >> 10, hw = r & 1023;
    const float* p = z + (size_t)b * 262144 + hw;
    double s = 0.0;
#pragma unroll 8
    for (int c = 0; c < 256; ++c) { float v = p[(size_t)c * 1024]; s += (double)v * (double)v; }
    S[r] = (float)s;
}
__global__ void f_rowsum_e(const float* __restrict__ emb, float* __restrict__ E) {
    int row = blockIdx.x * 4 + (threadIdx.x >> 6);
    int lane = threadIdx.x & 63;
    const float* p = emb + (size_t)row * 256;
    double s = 0.0;
#pragma unroll
    for (int i = 0; i < 4; ++i) { float v = p[lane + i * 64]; s += (double)v * (double)v; }
    for (int off = 32; off; off >>= 1) s += __shfl_down(s, off, 64);
    if (lane == 0) E[row] = (float)s;
}
__global__ __launch_bounds__(256, 4) void f_gemm_argmin(
    const float* __restrict__ z, const float* __restrict__ emb,
    const float* __restrict__ S, const float* __restrict__ E,
    unsigned long long* __restrict__ keys) {
    __shared__ __align__(16) float As[32][128];
    __shared__ __align__(16) float Bs[32][133];
    const int tid = threadIdx.x;
    const int tx = tid & 15, ty = tid >> 4;
    const int row0 = blockIdx.x * 128, col0 = blockIdx.y * 128;
    const int b = row0 >> 10, hw0 = row0 & 1023;
    const float* zb = z + (size_t)b * 262144 + hw0;
    float acc[8][8];
#pragma unroll
    for (int i = 0; i < 8; ++i)
#pragma unroll
        for (int j = 0; j < 8; ++j) acc[i][j] = 0.0f;
    for (int kt = 0; kt < 8; ++kt) {
        const int kbase = kt * 32;
#pragma unroll
        for (int it = 0; it < 4; ++it) {
            int e = tid + it * 256;
            int k = e >> 5, m4 = (e & 31) << 2;
            *(float4*)&As[k][m4] = *(const float4*)(zb + (size_t)(kbase + k) * 1024 + m4);
        }
#pragma unroll
        for (int it = 0; it < 4; ++it) {
            int e = tid + it * 256;
            int n = e >> 3, k4 = (e & 7) << 2;
            float4 v = *(const float4*)(emb + (size_t)(col0 + n) * 256 + kbase + k4);
            Bs[k4 + 0][n] = v.x; Bs[k4 + 1][n] = v.y;
            Bs[k4 + 2][n] = v.z; Bs[k4 + 3][n] = v.w;
        }
        __syncthreads();
#pragma unroll 8
        for (int k = 0; k < 32; ++k) {
            float4 a0 = *(const float4*)&As[k][tx * 4];
            float4 a1 = *(const float4*)&As[k][64 + tx * 4];
            float4 b0 = *(const float4*)&Bs[k][ty * 4];
            float4 b1 = *(const float4*)&Bs[k][64 + ty * 4];
            float a_[8] = {a0.x, a0.y, a0.z, a0.w, a1.x, a1.y, a1.z, a1.w};
            float b_[8] = {b0.x, b0.y, b0.z, b0.w, b1.x, b1.y, b1.z, b1.w};
#pragma unroll
            for (int i = 0; i < 8; ++i)
#pragma unroll
                for (int j = 0; j < 8; ++j) acc[i][j] += a_[i] * b_[j];
        }
        __syncthreads();
    }
    float4 S0 = *(const float4*)(S + row0 + tx * 4);
    float4 S1 = *(const float4*)(S + row0 + 64 + tx * 4);
    float4 E0 = *(const float4*)(E + col0 + ty * 4);
    float4 E1 = *(const float4*)(E + col0 + 64 + ty * 4);
    float Sr[8] = {S0.x, S0.y, S0.z, S0.w, S1.x, S1.y, S1.z, S1.w};
    float Ec[8] = {E0.x, E0.y, E0.z, E0.w, E1.x, E1.y, E1.z, E1.w};
    unsigned long long best[8];
#pragma unroll
    for (int i = 0; i < 8; ++i) best[i] = ~0ull;
#pragma unroll
    for (int j = 0; j < 8; ++j) {
        int col = col0 + ((j < 4) ? (ty * 4 + j) : (64 + ty * 4 + j - 4));
#pragma unroll
        for (int i = 0; i < 8; ++i) {
            float t = Sr[i] + Ec[j];
            float d = t - 2.0f * acc[i][j];
            unsigned ud = __float_as_uint(d);
            ud = (ud & 0x80000000u) ? ~ud : (ud | 0x80000000u);
            unsigned long long key = ((unsigned long long)ud << 32) | (unsigned)col;
            if (key < best[i]) best[i] = key;
        }
    }
    __syncthreads();
    unsigned long long* Sk = (unsigned long long*)&As[0][0];
#pragma unroll
    for (int i = 0; i < 4; ++i) {
        Sk[ty * 128 + tx * 4 + i] = best[i];
        Sk[ty * 128 + 64 + tx * 4 + i] = best[4 + i];
    }
    __syncthreads();
    if (tid < 128) {
        unsigned long long m = ~0ull;
#pragma unroll
        for (int t = 0; t < 16; ++t) {
            unsigned long long v = Sk[t * 128 + tid];
            m = v < m ? v : m;
        }
        atomicMin(&keys[row0 + tid], m);
    }
}
__global__ void f_merge(const unsigned long long* __restrict__ keys,
                        int* __restrict__ idx, float* __restrict__ idx_f) {
    int r = blockIdx.x * 256 + threadIdx.x;
    int bestj = (int)(keys[r] & 0xFFFFFFFFull);
    idx[r] = bestj;
    idx_f[r] = (float)bestj;
}

extern "C" void kernel_launch(void* const* d_in, const int* in_sizes, int n_in,
                              void* d_out, int out_size, void* d_ws, size_t ws_size,
                              hipStream_t stream) {
    const float* z   = (const float*)d_in[0];
    const float* emb = (const float*)d_in[1];
    float* out = (float*)d_out;
    float* ws  = (float*)d_ws;

    if (ws_size >= (size_t)WS_NEED_FLOATS * 4) {
        float* S = ws + OFF_S;
        float* E = ws + OFF_E;
        float* MARG = ws + OFF_MARG;
        int* IDX = (int*)(ws + OFF_IDX);
        _Float16* CH = (_Float16*)(ws + OFF_CH);
        unsigned short* ZFH = (unsigned short*)(ws + OFF_ZFH);
        unsigned short* EFH = (unsigned short*)(ws + OFF_EFH);
        float* LOSSP = ws + OFF_LOSSP;

        k_pre<<<384, 256, 0, stream>>>(z, emb, ws);
        dim3 g(NROWS / 256, NE / 256);
        k_gemm<<<g, 512, 0, stream>>>(ZFH, EFH, S, E, CH);
        k_rescore<<<NROWS / 32, 1024, 0, stream>>>(z, emb, S, E, MARG, ZFH, EFH,
                                                   CH, IDX, out + OUT_N + 1);
        k_out<<<NROWS / 32, 256, 0, stream>>>(z, emb, IDX, out, LOSSP);
        k_fin<<<1, 256, 0, stream>>>(LOSSP, out + OUT_N);
    } else {
        float* S = ws + FWS_S;
        float* E = ws + FWS_E;
        unsigned long long* KEYS = (unsigned long long*)(ws + FWS_KEY);
        int* IDX = (int*)(ws + FWS_IDX);
        float* LOSSP = ws + FWS_LOSSP;

        f_rowsum_z<<<NROWS / 256, 256, 0, stream>>>(z, S);
        f_rowsum_e<<<NE / 4, 256, 0, stream>>>(emb, E);
        hipMemsetAsync(KEYS, 0xFF, NROWS * sizeof(unsigned long long), stream);
        dim3 g(NROWS / 128, NE / 128);
        f_gemm_argmin<<<g, 256, 0, stream>>>(z, emb, S, E, KEYS);
        f_merge<<<NROWS / 256, 256, 0, stream>>>(KEYS, IDX, out + OUT_N + 1);
        k_out<<<NROWS / 32, 256, 0, stream>>>(z, emb, IDX, out, LOSSP);
        k_fin<<<1, 256, 0, stream>>>(LOSSP, out + OUT_N);
    }
}